// Round 12
// baseline (176.191 us; speedup 1.0000x reference)
//
#include <hip/hip_runtime.h>
#include <cstdint>
#include <cstddef>

typedef _Float16 f16;
typedef __attribute__((ext_vector_type(2))) __fp16 h16x2;   // builtin cvt_pkrtz/fdot2 type
typedef __attribute__((ext_vector_type(8))) _Float16 f16x8;
typedef __attribute__((ext_vector_type(4))) float f32x4;
typedef __attribute__((ext_vector_type(16))) float f32x16;
typedef const __attribute__((address_space(1))) uint32_t* gptr_t;
typedef __attribute__((address_space(3))) uint32_t* lptr_t;

#define DEV __device__ __forceinline__

DEV uint32_t pack2f16(float a, float b){
  union { f16 h[2]; uint32_t u; } p;
  p.h[0] = (f16)a; p.h[1] = (f16)b; return p.u;
}
DEV uint32_t cat2(f16 a, f16 b){
  union { f16 h[2]; uint32_t u; } p;
  p.h[0] = a; p.h[1] = b; return p.u;
}

// ---- problem constants
#define BB 2
#define SS 2048
#define HH 16
#define DD 64
#define NT (BB*SS)       // 4096 tokens
#define LLAT 256
#define LTOT 3328        // 2048 + 256 + 512 + 512
#define NTILE 26         // 3328 / 128 (128-key storage tiles)
#define LOG2E 1.44269504f
#define SC2 (0.125f*LOG2E)

// K' tile (per bh, per 128-key tile, 16KB): 16B chunk (key, dc) holds d=dc*8..+7,
//   at linear chunk pos key*8 + (dc ^ (key&7)).
// V' tile (16KB): 16B chunk (d, vc) holds PV k-slots s = vc*8+e; slot
//   s=16g+8hi+e -> key 32*(g>>1)+16*(g&1)+8*(e>>2)+4*hi+(e&3); chunk at
//   linear pos d*16 + (vc ^ (d&7)).
// Epilogue LDS transpose buffer Kl[128 keys][128 cols] f16, chunk-XOR'd:
#define KLIDX(key,col) (((key)<<7) + (((((col)>>3)^((key)&15)))<<3) + ((col)&7))

// ---------------------------------------------------------------- cvt f32->f16
__global__ void cvt_f32_f16(const float* __restrict__ src, f16* __restrict__ dst, size_t n){
  size_t i = ((size_t)blockIdx.x*blockDim.x + threadIdx.x)*4;
  if (i >= n) return;
  float4 v = *(const float4*)(src + i);
  uint2 o; o.x = pack2f16(v.x, v.y); o.y = pack2f16(v.z, v.w);
  *(uint2*)(dst + i) = o;
}

// ------------------------------- 5 weight transposes in one launch (z picks src)
__global__ void transpose_cvt5(const float* __restrict__ w0, const float* __restrict__ w1,
                               const float* __restrict__ w2, const float* __restrict__ w3,
                               const float* __restrict__ w4,
                               f16* __restrict__ dqkvg, f16* __restrict__ dout){
  __shared__ float t[32][33];
  int z = blockIdx.z;
  const float* src = z==0 ? w0 : z==1 ? w1 : z==2 ? w2 : z==3 ? w3 : w4;
  f16* dst = (z<4) ? (dqkvg + ((size_t)z<<20)) : dout;
  int tx = threadIdx.x, ty = threadIdx.y;
  int bx = blockIdx.x, by = blockIdx.y;
  #pragma unroll
  for (int i=0;i<4;i++){
    int r = ty + i*8;
    t[r][tx] = src[(size_t)(by*32 + r)*1024 + bx*32 + tx];
  }
  __syncthreads();
  #pragma unroll
  for (int i=0;i<4;i++){
    int r = ty + i*8;
    dst[(size_t)(bx*32 + r)*1024 + by*32 + tx] = (f16)t[tx][r];
  }
}

// GEMM staging: BK=32, double-buffered, 32KB total LDS.
// Layout: A0 @0, A1 @8K, B0 @16K, B1 @24K. Row = 64B (32 f16), 4 chunks/row;
// LDS chunk pc holds source k-chunk kc = pc ^ (row&3) (pre-swizzled source,
// linear GLDS dest). 4 lanes cover a 64B row.
#define GSTAGE(Aptr, Bptr, Kd, ktv, bb) do { \
  char* Asb_ = smem + ((bb)<<13); \
  char* Bsb_ = smem + 16384 + ((bb)<<13); \
  _Pragma("unroll") \
  for (int u=0; u<2; ++u){ \
    int c = tid + u*256; \
    int row = c>>2, kc = (c&3) ^ (row&3); \
    __builtin_amdgcn_global_load_lds((gptr_t)((Aptr) + (m0+row)*(Kd) + (ktv) + kc*8), \
                                     (lptr_t)(Asb_ + c*16), 16, 0, 0); \
    __builtin_amdgcn_global_load_lds((gptr_t)((Bptr) + (n0+row)*(Kd) + (ktv) + kc*8), \
                                     (lptr_t)(Bsb_ + c*16), 16, 0, 0); \
  } \
} while(0)

#define GCOMPUTE(bb) do { \
  const char* Asb = smem + ((bb)<<13); \
  const char* Bsb = smem + 16384 + ((bb)<<13); \
  f16x8 af[4], bf[4]; \
  _Pragma("unroll") \
  for (int i=0;i<4;i++){ \
    int R = wr*64+i*16+l16; \
    af[i] = *(const f16x8*)(Asb + R*64 + ((l4 ^ (R&3))<<4)); \
  } \
  _Pragma("unroll") \
  for (int j=0;j<4;j++){ \
    int R = wc*64+j*16+l16; \
    bf[j] = *(const f16x8*)(Bsb + R*64 + ((l4 ^ (R&3))<<4)); \
  } \
  __builtin_amdgcn_s_setprio(1); \
  _Pragma("unroll") \
  for (int i=0;i<4;i++) \
    _Pragma("unroll") \
    for (int j=0;j<4;j++) \
      acc[i][j] = __builtin_amdgcn_mfma_f32_16x16x32_f16(af[i], bf[j], acc[i][j], 0,0,0); \
  __builtin_amdgcn_s_setprio(0); \
} while(0)

// --------------------------------------------------------- fused QKVG GEMM
// [4096 x 4096] = x @ [wq|wk|wv|gw]. BK=32 dbuf, 1 barrier/K-step, 32KB LDS
// -> 4-5 blocks/CU. Epilogue fused per column region.
__launch_bounds__(256, 4)
__global__ void gemm_qkvg(const f16* __restrict__ A, const f16* __restrict__ Bt,
                          const float* __restrict__ qnw, const float* __restrict__ knw,
                          const float* __restrict__ fcos, const float* __restrict__ fsin,
                          const int* __restrict__ spp,
                          f16* __restrict__ Qall, char* __restrict__ Kt,
                          char* __restrict__ Vt, f16* __restrict__ gateS){
  __shared__ __align__(16) char smem[32768];
  const int tid = threadIdx.x;
  const int w = tid>>6, lane = tid&63;
  const int wr = w>>1, wc = w&1;
  const int l16 = lane&15, l4 = lane>>4;
  const int bid = blockIdx.x;
  const int x = bid&7, r_ = bid>>3;
  const int by = (x>>2)*16 + (r_>>3);
  const int bx = (x&3)*8 + (r_&7);
  const size_t m0 = (size_t)by*128, n0 = (size_t)bx*128;
  const int K = 1024;
  f32x4 acc[4][4];
  #pragma unroll
  for (int i=0;i<4;i++)
    #pragma unroll
    for (int j=0;j<4;j++) acc[i][j] = f32x4{0.f,0.f,0.f,0.f};

  GSTAGE(A, Bt, K, 0, 0);
  for (int t=0; t<32; ++t){
    __syncthreads();                       // drains STAGE(t); prior reads done
    if (t < 31) GSTAGE(A, Bt, K, (t+1)*32, (t+1)&1);
    GCOMPUTE(t&1);
  }

  // ----------------------------- epilogue
  const int region = bx >> 3;           // 0 q, 1 k, 2 v, 3 gate
  const int s0 = (int)(m0 & 2047);
  const int b_ = (int)(m0 >> 11);
  const int tt = s0 >> 7;
  f16* Kl = (f16*)smem;                 // 32KB transpose buffer (reuse)
  __syncthreads();                      // all LDS tile reads done

  if (region <= 1){
    const int sp = *spp;
    const int h = (bx&7)*2 + wc;
    const float* wnorm = (region==0 ? qnw : knw) + h*64;
    const float wsc = (region==0) ? SC2 : 1.f;
    const bool do_rope = h < 8;
    #pragma unroll
    for (int i=0;i<4;i++){
      float s2[4];
      #pragma unroll
      for (int r=0;r<4;r++)
        s2[r] = acc[i][0][r]*acc[i][0][r] + acc[i][1][r]*acc[i][1][r]
              + acc[i][2][r]*acc[i][2][r] + acc[i][3][r]*acc[i][3][r];
      #pragma unroll
      for (int msk=1; msk<16; msk<<=1)
        #pragma unroll
        for (int r=0;r<4;r++) s2[r] += __shfl_xor(s2[r], msk, 64);
      float rsq[4];
      #pragma unroll
      for (int r=0;r<4;r++) rsq[r] = rsqrtf(s2[r]*(1.f/64.f) + 1e-5f) * wsc;
      #pragma unroll
      for (int j=0;j<4;j++){
        const int chd = j*16 + l16;
        const float wn = wnorm[chd];
        float v_[4];
        #pragma unroll
        for (int r=0;r<4;r++) v_[r] = acc[i][j][r]*rsq[r]*wn;
        if (do_rope){
          const float sgn = (l16&1) ? 1.f : -1.f;
          #pragma unroll
          for (int r=0;r<4;r++){
            int s_ = s0 + wr*64 + i*16 + l4*4 + r;
            float c_ = fcos[(size_t)(sp+s_)*32 + j*8 + (l16>>1)];
            float sn = fsin[(size_t)(sp+s_)*32 + j*8 + (l16>>1)];
            float pr = __shfl_xor(v_[r], 1, 64);
            v_[r] = v_[r]*c_ + sgn*pr*sn;
          }
        }
        #pragma unroll
        for (int r=0;r<4;r++){
          int key = wr*64 + i*16 + l4*4 + r;
          Kl[KLIDX(key, wc*64 + chd)] = (f16)v_[r];
        }
      }
    }
    __syncthreads();
    #pragma unroll
    for (int u=0;u<8;u++){
      int cc = tid + u*256;
      int h_loc = cc>>10, cl = cc&1023;
      int key = cl>>3, pc = cl&7;
      size_t bh2 = (size_t)(b_*16 + (bx&7)*2 + h_loc);
      if (region==0){
        f16x8 vv = *(const f16x8*)(Kl + KLIDX(key, h_loc*64 + pc*8));
        *(f16x8*)(Qall + (bh2*SS + s0 + key)*64 + pc*8) = vv;
      } else {
        int dc = pc ^ (key&7);
        f16x8 vv = *(const f16x8*)(Kl + KLIDX(key, h_loc*64 + dc*8));
        *(f16x8*)(Kt + (bh2*NTILE + tt)*16384 + (size_t)cl*16) = vv;
      }
    }
  } else if (region == 2){
    #pragma unroll
    for (int i=0;i<4;i++)
      #pragma unroll
      for (int j=0;j<4;j++)
        #pragma unroll
        for (int r=0;r<4;r++){
          int key = wr*64 + i*16 + l4*4 + r;
          Kl[KLIDX(key, wc*64 + j*16 + l16)] = (f16)acc[i][j][r];
        }
    __syncthreads();
    #pragma unroll
    for (int u=0;u<8;u++){
      int cc = tid + u*256;
      int h_loc = cc>>10, c = cc&1023;
      int d = c>>4, vc = (c&15)^(d&7);
      int g = vc>>1, hi2 = vc&1;
      int kb_ = 32*(g>>1) + 16*(g&1) + 4*hi2;
      int col = h_loc*64 + d;
      f16 a0 = Kl[KLIDX(kb_+0,col)],  a1 = Kl[KLIDX(kb_+1,col)];
      f16 a2 = Kl[KLIDX(kb_+2,col)],  a3 = Kl[KLIDX(kb_+3,col)];
      f16 a4 = Kl[KLIDX(kb_+8,col)],  a5 = Kl[KLIDX(kb_+9,col)];
      f16 a6 = Kl[KLIDX(kb_+10,col)], a7 = Kl[KLIDX(kb_+11,col)];
      uint4 o; o.x = cat2(a0,a1); o.y = cat2(a2,a3); o.z = cat2(a4,a5); o.w = cat2(a6,a7);
      size_t bh2 = (size_t)(b_*16 + (bx&7)*2 + h_loc);
      *(uint4*)(Vt + (bh2*NTILE + tt)*16384 + (size_t)c*16) = o;
    }
  } else {
    #pragma unroll
    for (int i=0;i<4;i++)
      #pragma unroll
      for (int j=0;j<4;j++)
        #pragma unroll
        for (int r=0;r<4;r++){
          int key = wr*64 + i*16 + l4*4 + r;
          float v_ = 1.f/(1.f + __builtin_amdgcn_exp2f(-acc[i][j][r]*LOG2E));
          Kl[KLIDX(key, wc*64 + j*16 + l16)] = (f16)v_;
        }
    __syncthreads();
    #pragma unroll
    for (int u=0;u<8;u++){
      int cc = tid + u*256;
      int key = cc>>4, ch = cc&15;
      f16x8 vv = *(const f16x8*)(Kl + KLIDX(key, ch*8));
      *(f16x8*)(gateS + (size_t)(m0 + key)*1024 + (bx&7)*128 + ch*8) = vv;
    }
  }
}

// ----------------------------------------------- final projection GEMM (f32 C)
__launch_bounds__(256, 4)
__global__ void gemm_out(const f16* __restrict__ A, const f16* __restrict__ Bt,
                         float* __restrict__ C){
  __shared__ __align__(16) char smem[32768];
  const int tid = threadIdx.x;
  const int w = tid>>6, lane = tid&63;
  const int wr = w>>1, wc = w&1;
  const int l16 = lane&15, l4 = lane>>4;
  const int bid = blockIdx.x;
  const int by = (bid&7)*4 + ((bid>>3)>>3);
  const int bx = (bid>>3)&7;
  const size_t m0 = (size_t)by*128, n0 = (size_t)bx*128;
  const int K = 1024;
  f32x4 acc[4][4];
  #pragma unroll
  for (int i=0;i<4;i++)
    #pragma unroll
    for (int j=0;j<4;j++) acc[i][j] = f32x4{0.f,0.f,0.f,0.f};

  GSTAGE(A, Bt, K, 0, 0);
  for (int t=0; t<32; ++t){
    __syncthreads();
    if (t < 31) GSTAGE(A, Bt, K, (t+1)*32, (t+1)&1);
    GCOMPUTE(t&1);
  }
  #pragma unroll
  for (int i=0;i<4;i++)
    #pragma unroll
    for (int j=0;j<4;j++)
      #pragma unroll
      for (int r=0;r<4;r++)
        C[(m0 + wr*64 + i*16 + l4*4 + r)*1024 + n0 + wc*64 + j*16 + l16] = acc[i][j][r];
}

// -------------------------------------------- pack ALL context K -> K' tiles
__launch_bounds__(256)
__global__ void pack_k_all(const float* __restrict__ lat, const float* __restrict__ txt,
                           const float* __restrict__ spk, char* __restrict__ Kt){
  int unit = blockIdx.x*16 + (threadIdx.x>>4);
  int ll = threadIdx.x & 15;
  int l = unit % 1280; int bh = unit / 1280;
  int b = bh >> 4, h = bh & 15;
  const float* src; int nL, li, l0;
  if (l < 256)      { src = lat; nL = 256; li = l;     l0 = 2048; }
  else if (l < 768) { src = txt; nL = 512; li = l-256; l0 = 2304; }
  else              { src = spk; nL = 512; li = l-768; l0 = 2816; }
  float4 v = *(const float4*)(src + (((size_t)b*nL + li)*16 + h)*64 + ll*4);
  uint2 o; o.x = pack2f16(v.x, v.y); o.y = pack2f16(v.z, v.w);
  int s = l0 + li; int tt = s >> 7, kl = s & 127;
  *(uint2*)(Kt + ((size_t)bh*NTILE + tt)*16384
               + (kl*8 + ((ll>>1) ^ (kl&7)))*16 + (ll&1)*8) = o;
}

// --------------------------- pack ALL context V -> V' tiles (sigma + bank XOR)
__launch_bounds__(256)
__global__ void pack_v_all(const float* __restrict__ lat, const float* __restrict__ txt,
                           const float* __restrict__ spk, char* __restrict__ Vt){
  __shared__ float t[128*68];
  const int bh = blockIdx.y, b = bh>>4, h = bh&15;
  const int tz = blockIdx.x;              // 0..9 -> storage tile 16+tz
  const float* src; int tl, nB;
  if (tz < 2)      { src = lat; tl = tz;   nB = 256; }
  else if (tz < 6) { src = txt; tl = tz-2; nB = 512; }
  else             { src = spk; tl = tz-6; nB = 512; }
  const float* sb = src + ((size_t)b*nB + tl*128)*1024 + h*64;
  const int tid = threadIdx.x;
  {
    int row = tid >> 1, half = tid & 1;
    #pragma unroll
    for (int i=0;i<8;i++){
      float4 v = *(const float4*)(sb + (size_t)row*1024 + half*32 + i*4);
      *(float4*)(&t[row*68 + half*32 + i*4]) = v;
    }
  }
  __syncthreads();
  char* dstb = Vt + ((size_t)bh*NTILE + 16 + tz)*16384;
  #pragma unroll
  for (int u=0;u<4;u++){
    int c = tid + u*256;
    int d = c >> 4;
    int vc = (c & 15) ^ (d & 7);
    int g = vc >> 1, hi = vc & 1;
    int kb_ = 32*(g>>1) + 16*(g&1) + 4*hi;
    uint4 o;
    o.x = pack2f16(t[(kb_+0)*68+d],  t[(kb_+1)*68+d]);
    o.y = pack2f16(t[(kb_+2)*68+d],  t[(kb_+3)*68+d]);
    o.z = pack2f16(t[(kb_+8)*68+d],  t[(kb_+9)*68+d]);
    o.w = pack2f16(t[(kb_+10)*68+d], t[(kb_+11)*68+d]);
    *(uint4*)(dstb + c*16) = o;
  }
}

// -------------------------------------------------------------- flash attention
// Split-K x4 (fixed-max softmax => partials add exactly). 64-key dbuf tiles,
// 13 tiles per block -> 2048 blocks, 5 blocks/CU (20 waves/CU latency hiding).
// Fully-masked latent tiles (always inside split 2) skipped via runtime remap.
__launch_bounds__(256, 4)
__global__ void attn_fwd(const f16* __restrict__ Qall, const char* __restrict__ Kt,
                         const char* __restrict__ Vt, const int* __restrict__ spp,
                         float* __restrict__ po0, float* __restrict__ po1,
                         float* __restrict__ po2, float* __restrict__ po3,
                         float* __restrict__ plsum){
  __shared__ __align__(16) char Ks[2][8192];
  __shared__ __align__(16) char Vs[2][8192];
  const int sp = *spp;
  const int tid = threadIdx.x, lane = tid & 63, w = tid >> 6;
  const int l31 = lane & 31, hi = lane >> 5, l7 = lane & 7;
  const int bid = blockIdx.x;
  const int bh = (bid&7)*4 + ((bid>>3)>>6);   // 256 blocks per XCD share 4 bh
  const int rem = (bid>>3)&63;
  const int qb = rem>>2, ksp = rem&3;
  const int b = bh >> 4, h = bh & 15;
  const int q0w = qb*128 + w*32;
  const f16*  Qb = Qall + (size_t)bh*SS*DD;
  const char* Kb = Kt + (size_t)bh*NTILE*16384;
  const char* Vb = Vt + (size_t)bh*NTILE*16384;

  // tile remap: skip fully-masked latent 64-key tiles (T in [Ms,36), all in
  // split 2's range [26,39))
  const int vl   = min(256, (sp + 3) >> 2);   // valid latent keys
  const int Ms   = 32 + ((vl + 63) >> 6);     // first fully-masked tile (32..36)
  const int skip = 36 - Ms;                   // 0..4 tiles skipped
  const int nt   = (ksp==2) ? (13 - skip) : 13;
  #define TMAP(ti) ((ksp==2) ? ((26 + (ti)) < Ms ? (26 + (ti)) : (26 + (ti) + skip)) \
                             : (13*ksp + (ti)))

  f16x8 qf[4];
  {
    const f16* qrow = Qb + (size_t)(q0w + l31)*DD + hi*8;
    #pragma unroll
    for (int ks=0; ks<4; ks++) qf[ks] = *(const f16x8*)(qrow + ks*16);
  }

  f32x16 oA = {0,0,0,0,0,0,0,0,0,0,0,0,0,0,0,0};
  f32x16 oB = {0,0,0,0,0,0,0,0,0,0,0,0,0,0,0,0};
  float lsum0 = 0.f, lsum1 = 0.f;
  const h16x2 ones2 = {(__fp16)1.f, (__fp16)1.f};

  #define STAGE(bi, T) do { \
    const char* kb_ = Kb + (size_t)((T)>>1)*16384 + ((T)&1)*8192; \
    const char* vb_ = Vb + (size_t)((T)>>1)*16384 + ((T)&1)*128; \
    _Pragma("unroll") \
    for (int u=0; u<2; ++u){ \
      int c = tid + u*256; \
      __builtin_amdgcn_global_load_lds((gptr_t)(kb_ + c*16), (lptr_t)(&Ks[bi][c*16]), 16, 0, 0); \
      __builtin_amdgcn_global_load_lds((gptr_t)(vb_ + (size_t)(c>>3)*256 + (c&7)*16), \
                                       (lptr_t)(&Vs[bi][c*16]), 16, 0, 0); \
    } \
  } while(0)

  STAGE(0, TMAP(0));
  for (int ti = 0; ti < nt; ++ti){
    __syncthreads();
    if (ti < nt-1) STAGE((ti+1)&1, TMAP(ti+1));
    const char* Ksb = Ks[ti&1];
    const char* Vsb = Vs[ti&1];
    const int T = TMAP(ti);
    const bool maskt = (unsigned)(T-32) < 4u;   // latent 64-key tiles 32..35
    const int ktl = T*64 - 2048;
    #pragma unroll
    for (int kb=0; kb<2; ++kb){
      f16x8 kf[4];
      #pragma unroll
      for (int ks=0; ks<4; ks++)
        kf[ks] = *(const f16x8*)(Ksb + (32*kb + l31)*128 + (((2*ks+hi) ^ l7))*16);
      f32x16 acc = {0,0,0,0,0,0,0,0,0,0,0,0,0,0,0,0};
      __builtin_amdgcn_s_setprio(1);
      #pragma unroll
      for (int ks=0; ks<4; ks++)
        acc = __builtin_amdgcn_mfma_f32_32x32x16_f16(kf[ks], qf[ks], acc, 0,0,0);
      __builtin_amdgcn_s_setprio(0);
      if (maskt){
        #pragma unroll
        for (int r=0;r<16;r++){
          int kk = ktl + kb*32 + (r&3) + 8*(r>>2) + 4*hi;
          if (kk*4 >= sp) acc[r] = -1e5f;
        }
      }
      // fixed-max softmax: p = 2^s (bounded by 2^11.54 < f16 max).
      // pkrtz packs the pair in 1 instr; fdot2 with ones accumulates lsum
      // from the SAME rounded f16 values that feed PV. Two lsum chains (ILP).
      uint32_t pk[8];
      #pragma unroll
      for (int i=0;i<8;i++){
        float p0 = __builtin_amdgcn_exp2f(acc[2*i]);
        float p1 = __builtin_amdgcn_exp2f(acc[2*i+1]);
        h16x2 h2 = __builtin_amdgcn_cvt_pkrtz(p0, p1);
#if __has_builtin(__builtin_amdgcn_fdot2)
        if (i & 1) lsum1 = __builtin_amdgcn_fdot2(h2, ones2, lsum1, false);
        else       lsum0 = __builtin_amdgcn_fdot2(h2, ones2, lsum0, false);
#else
        if (i & 1) lsum1 += (float)h2[0] + (float)h2[1];
        else       lsum0 += (float)h2[0] + (float)h2[1];
#endif
        union { h16x2 v; uint32_t u; } cv; cv.v = h2; pk[i] = cv.u;
      }
      __builtin_amdgcn_s_setprio(1);
      #pragma unroll
      for (int gg=0; gg<2; gg++){
        union { uint4 u; f16x8 v; } pa;
        pa.u = make_uint4(pk[4*gg], pk[4*gg+1], pk[4*gg+2], pk[4*gg+3]);
        int cofs = ((2*(2*kb+gg) + hi) ^ l7)*16;
        f16x8 v0 = *(const f16x8*)(Vsb + l31*128 + cofs);
        f16x8 v1 = *(const f16x8*)(Vsb + (32+l31)*128 + cofs);
        oA = __builtin_amdgcn_mfma_f32_32x32x16_f16(pa.v, v0, oA, 0,0,0);
        oB = __builtin_amdgcn_mfma_f32_32x32x16_f16(pa.v, v1, oB, 0,0,0);
      }
      __builtin_amdgcn_s_setprio(0);
    }
  }
  #undef STAGE
  #undef TMAP

  float lsum = lsum0 + lsum1;
  lsum += __shfl_xor(lsum, 32, 64);
  float* pob = (ksp==0) ? po0 : (ksp==1) ? po1 : (ksp==2) ? po2 : po3;
  #pragma unroll
  for (int r=0;r<16;r++){
    int qo = (r&3) + 8*(r>>2) + 4*hi;
    size_t token = (size_t)(b*SS + q0w + qo);
    pob[token*1024 + h*64 + l31]      = oA[r];
    pob[token*1024 + h*64 + 32 + l31] = oB[r];
  }
  if (hi == 0){
    size_t token = (size_t)(b*SS + q0w + l31);
    plsum[(size_t)ksp*NT*HH + token*HH + h] = lsum;
  }
}

// ------------------------------------ combine: (sum o_j)/(sum l_j) * sigma(gate)
__launch_bounds__(256)
__global__ void attn_combine(const float* __restrict__ po0, const float* __restrict__ po1,
                             const float* __restrict__ po2, const float* __restrict__ po3,
                             const float* __restrict__ plsum,
                             const f16* __restrict__ gateS, f16* __restrict__ go){
  int idx = blockIdx.x*256 + threadIdx.x;   // NT*256 threads, 4 cols each
  int token = idx >> 8;
  int col = (idx & 255)*4;
  int h = col >> 6;
  size_t off = (size_t)token*1024 + col;
  float4 p0 = *(const float4*)(po0 + off);
  float4 p1 = *(const float4*)(po1 + off);
  float4 p2 = *(const float4*)(po2 + off);
  float4 p3 = *(const float4*)(po3 + off);
  size_t li = (size_t)token*HH + h;
  float ls = plsum[li] + plsum[(size_t)NT*HH + li]
           + plsum[(size_t)2*NT*HH + li] + plsum[(size_t)3*NT*HH + li];
  float inv = 1.f / ls;
  const f16* gp = gateS + (size_t)token*1024 + col;
  float g0 = (float)gp[0], g1 = (float)gp[1], g2 = (float)gp[2], g3 = (float)gp[3];
  uint2 o;
  o.x = pack2f16((p0.x+p1.x+p2.x+p3.x)*inv*g0, (p0.y+p1.y+p2.y+p3.y)*inv*g1);
  o.y = pack2f16((p0.z+p1.z+p2.z+p3.z)*inv*g2, (p0.w+p1.w+p2.w+p3.w)*inv*g3);
  *(uint2*)(go + (size_t)token*1024 + col) = o;
}

// ---------------------------------------------------------------------- launch
extern "C" void kernel_launch(void* const* d_in, const int* in_sizes, int n_in,
                              void* d_out, int out_size, void* d_ws, size_t ws_size,
                              hipStream_t stream){
  const float* x        = (const float*)d_in[0];
  const float* fcos     = (const float*)d_in[3];
  const float* fsin     = (const float*)d_in[4];
  const float* kv_txt_k = (const float*)d_in[5];
  const float* kv_txt_v = (const float*)d_in[6];
  const float* kv_spk_k = (const float*)d_in[7];
  const float* kv_spk_v = (const float*)d_in[8];
  const float* kv_lat_k = (const float*)d_in[9];
  const float* kv_lat_v = (const float*)d_in[10];
  const int*   sp       = (const int*)d_in[11];
  const float* wq       = (const float*)d_in[12];
  const float* wk       = (const float*)d_in[13];
  const float* wv       = (const float*)d_in[14];
  const float* gw       = (const float*)d_in[15];
  const float* wo       = (const float*)d_in[16];
  const float* qnw      = (const float*)d_in[17];
  const float* knw      = (const float*)d_in[18];
  float* out = (float*)d_out;
  char* ws = (char*)d_ws;

  // layout (high-water ~122.7MB; po2 overlays xh+WtQKVG, dead after gemm_qkvg)
  f16*   xh     = (f16*)  (ws + 0);          // 8 MB
  f16*   WtQKVG = (f16*)  (ws + 8388608);    // 8 MB
  f16*   WtO    = (f16*)  (ws + 16777216);   // 2 MB
  f16*   gateS  = (f16*)  (ws + 18874368);   // 8 MB  f16 sigma(gate)
  f16*   Qall   = (f16*)  (ws + 27262976);   // 8 MB  (B,H,S,D)
  char*  Kt     = (char*) (ws + 35651584);   // 13.6 MB K' tiles
  char*  Vt     = (char*) (ws + 49283072);   // 13.6 MB V' tiles
  f16*   go     = (f16*)  (ws + 62914560);   // 8 MB
  float* plsum  = (float*)(ws + 71303168);   // 1 MB (4 splits)
  float* po0    = (float*)(ws + 72351744);   // 16 MB
  float* po1    = (float*)(ws + 89128960);   // 16 MB
  float* po2    = (float*)(ws + 0);          // 16 MB (overlay)
  float* po3    = (float*)(ws + 105906176);  // 16 MB -> ends 122,683,392

  cvt_f32_f16<<<4096, 256, 0, stream>>>(x, xh, (size_t)NT*1024);
  dim3 tb(32,8);
  transpose_cvt5<<<dim3(32,32,5), tb, 0, stream>>>(wq, wk, wv, gw, wo, WtQKVG, WtO);

  gemm_qkvg<<<1024, 256, 0, stream>>>(xh, WtQKVG, qnw, knw, fcos, fsin, sp,
                                      Qall, Kt, Vt, gateS);

  pack_k_all<<<2560, 256, 0, stream>>>(kv_lat_k, kv_txt_k, kv_spk_k, Kt);
  pack_v_all<<<dim3(10,32), 256, 0, stream>>>(kv_lat_v, kv_txt_v, kv_spk_v, Vt);

  attn_fwd<<<2048, 256, 0, stream>>>(Qall, Kt, Vt, sp, po0, po1, po2, po3, plsum);
  attn_combine<<<4096, 256, 0, stream>>>(po0, po1, po2, po3, plsum, gateS, go);

  gemm_out<<<256, 256, 0, stream>>>(go, WtO, out);
}

// Round 13
// 173.973 us; speedup vs baseline: 1.0127x; 1.0127x over previous
//
#include <hip/hip_runtime.h>
#include <cstdint>
#include <cstddef>

typedef _Float16 f16;
typedef __attribute__((ext_vector_type(2))) __fp16 h16x2;   // builtin cvt_pkrtz/fdot2 type
typedef __attribute__((ext_vector_type(8))) _Float16 f16x8;
typedef __attribute__((ext_vector_type(4))) float f32x4;
typedef __attribute__((ext_vector_type(16))) float f32x16;
typedef const __attribute__((address_space(1))) uint32_t* gptr_t;
typedef __attribute__((address_space(3))) uint32_t* lptr_t;

#define DEV __device__ __forceinline__

DEV uint32_t pack2f16(float a, float b){
  union { f16 h[2]; uint32_t u; } p;
  p.h[0] = (f16)a; p.h[1] = (f16)b; return p.u;
}
DEV uint32_t cat2(f16 a, f16 b){
  union { f16 h[2]; uint32_t u; } p;
  p.h[0] = a; p.h[1] = b; return p.u;
}

// ---- problem constants
#define BB 2
#define SS 2048
#define HH 16
#define DD 64
#define NT (BB*SS)       // 4096 tokens
#define LLAT 256
#define LTOT 3328        // 2048 + 256 + 512 + 512
#define NTILE 26         // 3328 / 128 (128-key storage tiles)
#define LOG2E 1.44269504f
#define SC2 (0.125f*LOG2E)

// K' tile (per bh, per 128-key tile, 16KB): 16B chunk (key, dc) holds d=dc*8..+7,
//   at linear chunk pos key*8 + (dc ^ (key&7)).
// V' tile (16KB): 16B chunk (d, vc) holds PV k-slots s = vc*8+e; slot
//   s=16g+8hi+e -> key 32*(g>>1)+16*(g&1)+8*(e>>2)+4*hi+(e&3); chunk at
//   linear pos d*16 + (vc ^ (d&7)).
// Epilogue LDS transpose buffer Kl[128 keys][128 cols] f16, chunk-XOR'd:
#define KLIDX(key,col) (((key)<<7) + (((((col)>>3)^((key)&15)))<<3) + ((col)&7))

// ---------------------------------------------------------------- cvt f32->f16
__global__ void cvt_f32_f16(const float* __restrict__ src, f16* __restrict__ dst, size_t n){
  size_t i = ((size_t)blockIdx.x*blockDim.x + threadIdx.x)*4;
  if (i >= n) return;
  float4 v = *(const float4*)(src + i);
  uint2 o; o.x = pack2f16(v.x, v.y); o.y = pack2f16(v.z, v.w);
  *(uint2*)(dst + i) = o;
}

// ------------------------------- 5 weight transposes in one launch (z picks src)
__global__ void transpose_cvt5(const float* __restrict__ w0, const float* __restrict__ w1,
                               const float* __restrict__ w2, const float* __restrict__ w3,
                               const float* __restrict__ w4,
                               f16* __restrict__ dqkvg, f16* __restrict__ dout){
  __shared__ float t[32][33];
  int z = blockIdx.z;
  const float* src = z==0 ? w0 : z==1 ? w1 : z==2 ? w2 : z==3 ? w3 : w4;
  f16* dst = (z<4) ? (dqkvg + ((size_t)z<<20)) : dout;
  int tx = threadIdx.x, ty = threadIdx.y;
  int bx = blockIdx.x, by = blockIdx.y;
  #pragma unroll
  for (int i=0;i<4;i++){
    int r = ty + i*8;
    t[r][tx] = src[(size_t)(by*32 + r)*1024 + bx*32 + tx];
  }
  __syncthreads();
  #pragma unroll
  for (int i=0;i<4;i++){
    int r = ty + i*8;
    dst[(size_t)(bx*32 + r)*1024 + by*32 + tx] = (f16)t[tx][r];
  }
}

// GEMM staging (double-buffered, 64KB): row-major LDS rows of 128B, chunk pc
// within a row holds source k-chunk kc = pc ^ (row&7) (pre-swizzled source,
// linear GLDS dest). Coalesced: 8 lanes cover a full 128B row.
#define GSTAGE(Aptr, Bptr, Kd, ktv, bb) do { \
  char* Asb_ = smem + ((bb)<<14); \
  char* Bsb_ = smem + 32768 + ((bb)<<14); \
  _Pragma("unroll") \
  for (int u=0; u<4; ++u){ \
    int c = tid + u*256; \
    int row = c>>3, kc = (c&7) ^ (row&7); \
    __builtin_amdgcn_global_load_lds((gptr_t)((Aptr) + (m0+row)*(Kd) + (ktv) + kc*8), \
                                     (lptr_t)(Asb_ + c*16), 16, 0, 0); \
    __builtin_amdgcn_global_load_lds((gptr_t)((Bptr) + (n0+row)*(Kd) + (ktv) + kc*8), \
                                     (lptr_t)(Bsb_ + c*16), 16, 0, 0); \
  } \
} while(0)

// --------------------------------------------------------- fused QKVG GEMM
// [4096 x 4096] = x @ [wq|wk|wv|gw]. Double-buffered, 1 barrier/K-step.
// Epilogue fused per column region: q/k RMS+RoPE+pack, v -> V' tiles (sigma),
// gate -> sigmoid. All global writes coalesced 16B.
__launch_bounds__(256, 2)
__global__ void gemm_qkvg(const f16* __restrict__ A, const f16* __restrict__ Bt,
                          const float* __restrict__ qnw, const float* __restrict__ knw,
                          const float* __restrict__ fcos, const float* __restrict__ fsin,
                          const int* __restrict__ spp,
                          f16* __restrict__ Qall, char* __restrict__ Kt,
                          char* __restrict__ Vt, f16* __restrict__ gateS){
  __shared__ __align__(16) char smem[65536];
  const int tid = threadIdx.x;
  const int w = tid>>6, lane = tid&63;
  const int wr = w>>1, wc = w&1;
  const int l16 = lane&15, l4 = lane>>4;
  const int bid = blockIdx.x;
  const int x = bid&7, r_ = bid>>3;
  const int by = (x>>2)*16 + (r_>>3);
  const int bx = (x&3)*8 + (r_&7);
  const size_t m0 = (size_t)by*128, n0 = (size_t)bx*128;
  const int K = 1024;
  f32x4 acc[4][4];
  #pragma unroll
  for (int i=0;i<4;i++)
    #pragma unroll
    for (int j=0;j<4;j++) acc[i][j] = f32x4{0.f,0.f,0.f,0.f};

  GSTAGE(A, Bt, K, 0, 0);
  for (int t=0; t<16; ++t){
    __syncthreads();                       // drains STAGE(t)
    if (t < 15) GSTAGE(A, Bt, K, (t+1)*64, (t+1)&1);
    const char* Asb = smem + ((t&1)<<14);
    const char* Bsb = smem + 32768 + ((t&1)<<14);
    #pragma unroll
    for (int h2=0; h2<2; h2++){
      f16x8 af[4], bf[4];
      #pragma unroll
      for (int i=0;i<4;i++){
        int R = wr*64+i*16+l16;
        af[i] = *(const f16x8*)(Asb + R*128 + (((h2*4+l4)^(R&7))<<4));
      }
      #pragma unroll
      for (int j=0;j<4;j++){
        int R = wc*64+j*16+l16;
        bf[j] = *(const f16x8*)(Bsb + R*128 + (((h2*4+l4)^(R&7))<<4));
      }
      __builtin_amdgcn_s_setprio(1);
      #pragma unroll
      for (int i=0;i<4;i++)
        #pragma unroll
        for (int j=0;j<4;j++)
          acc[i][j] = __builtin_amdgcn_mfma_f32_16x16x32_f16(af[i], bf[j], acc[i][j], 0,0,0);
      __builtin_amdgcn_s_setprio(0);
    }
  }

  // ----------------------------- epilogue
  const int region = bx >> 3;           // 0 q, 1 k, 2 v, 3 gate
  const int s0 = (int)(m0 & 2047);
  const int b_ = (int)(m0 >> 11);
  const int tt = s0 >> 7;
  f16* Kl = (f16*)smem;                 // 32KB transpose buffer (reuse)
  __syncthreads();                      // all LDS tile reads done

  if (region <= 1){
    const int sp = *spp;
    const int h = (bx&7)*2 + wc;
    const float* wnorm = (region==0 ? qnw : knw) + h*64;
    const float wsc = (region==0) ? SC2 : 1.f;
    const bool do_rope = h < 8;
    #pragma unroll
    for (int i=0;i<4;i++){
      float s2[4];
      #pragma unroll
      for (int r=0;r<4;r++)
        s2[r] = acc[i][0][r]*acc[i][0][r] + acc[i][1][r]*acc[i][1][r]
              + acc[i][2][r]*acc[i][2][r] + acc[i][3][r]*acc[i][3][r];
      #pragma unroll
      for (int msk=1; msk<16; msk<<=1)
        #pragma unroll
        for (int r=0;r<4;r++) s2[r] += __shfl_xor(s2[r], msk, 64);
      float rsq[4];
      #pragma unroll
      for (int r=0;r<4;r++) rsq[r] = rsqrtf(s2[r]*(1.f/64.f) + 1e-5f) * wsc;
      #pragma unroll
      for (int j=0;j<4;j++){
        const int chd = j*16 + l16;
        const float wn = wnorm[chd];
        float v_[4];
        #pragma unroll
        for (int r=0;r<4;r++) v_[r] = acc[i][j][r]*rsq[r]*wn;
        if (do_rope){
          const float sgn = (l16&1) ? 1.f : -1.f;
          #pragma unroll
          for (int r=0;r<4;r++){
            int s_ = s0 + wr*64 + i*16 + l4*4 + r;
            float c_ = fcos[(size_t)(sp+s_)*32 + j*8 + (l16>>1)];
            float sn = fsin[(size_t)(sp+s_)*32 + j*8 + (l16>>1)];
            float pr = __shfl_xor(v_[r], 1, 64);
            v_[r] = v_[r]*c_ + sgn*pr*sn;
          }
        }
        #pragma unroll
        for (int r=0;r<4;r++){
          int key = wr*64 + i*16 + l4*4 + r;
          Kl[KLIDX(key, wc*64 + chd)] = (f16)v_[r];
        }
      }
    }
    __syncthreads();
    #pragma unroll
    for (int u=0;u<8;u++){
      int cc = tid + u*256;
      int h_loc = cc>>10, cl = cc&1023;
      int key = cl>>3, pc = cl&7;
      size_t bh2 = (size_t)(b_*16 + (bx&7)*2 + h_loc);
      if (region==0){
        f16x8 vv = *(const f16x8*)(Kl + KLIDX(key, h_loc*64 + pc*8));
        *(f16x8*)(Qall + (bh2*SS + s0 + key)*64 + pc*8) = vv;
      } else {
        int dc = pc ^ (key&7);
        f16x8 vv = *(const f16x8*)(Kl + KLIDX(key, h_loc*64 + dc*8));
        *(f16x8*)(Kt + (bh2*NTILE + tt)*16384 + (size_t)cl*16) = vv;
      }
    }
  } else if (region == 2){
    #pragma unroll
    for (int i=0;i<4;i++)
      #pragma unroll
      for (int j=0;j<4;j++)
        #pragma unroll
        for (int r=0;r<4;r++){
          int key = wr*64 + i*16 + l4*4 + r;
          Kl[KLIDX(key, wc*64 + j*16 + l16)] = (f16)acc[i][j][r];
        }
    __syncthreads();
    #pragma unroll
    for (int u=0;u<8;u++){
      int cc = tid + u*256;
      int h_loc = cc>>10, c = cc&1023;
      int d = c>>4, vc = (c&15)^(d&7);
      int g = vc>>1, hi2 = vc&1;
      int kb_ = 32*(g>>1) + 16*(g&1) + 4*hi2;
      int col = h_loc*64 + d;
      f16 a0 = Kl[KLIDX(kb_+0,col)],  a1 = Kl[KLIDX(kb_+1,col)];
      f16 a2 = Kl[KLIDX(kb_+2,col)],  a3 = Kl[KLIDX(kb_+3,col)];
      f16 a4 = Kl[KLIDX(kb_+8,col)],  a5 = Kl[KLIDX(kb_+9,col)];
      f16 a6 = Kl[KLIDX(kb_+10,col)], a7 = Kl[KLIDX(kb_+11,col)];
      uint4 o; o.x = cat2(a0,a1); o.y = cat2(a2,a3); o.z = cat2(a4,a5); o.w = cat2(a6,a7);
      size_t bh2 = (size_t)(b_*16 + (bx&7)*2 + h_loc);
      *(uint4*)(Vt + (bh2*NTILE + tt)*16384 + (size_t)c*16) = o;
    }
  } else {
    #pragma unroll
    for (int i=0;i<4;i++)
      #pragma unroll
      for (int j=0;j<4;j++)
        #pragma unroll
        for (int r=0;r<4;r++){
          int key = wr*64 + i*16 + l4*4 + r;
          float v_ = 1.f/(1.f + __builtin_amdgcn_exp2f(-acc[i][j][r]*LOG2E));
          Kl[KLIDX(key, wc*64 + j*16 + l16)] = (f16)v_;
        }
    __syncthreads();
    #pragma unroll
    for (int u=0;u<8;u++){
      int cc = tid + u*256;
      int key = cc>>4, ch = cc&15;
      f16x8 vv = *(const f16x8*)(Kl + KLIDX(key, ch*8));
      *(f16x8*)(gateS + (size_t)(m0 + key)*1024 + (bx&7)*128 + ch*8) = vv;
    }
  }
}

// ----------------------------------------------- final projection GEMM (f32 C)
__launch_bounds__(256, 2)
__global__ void gemm_out(const f16* __restrict__ A, const f16* __restrict__ Bt,
                         float* __restrict__ C){
  __shared__ __align__(16) char smem[65536];
  const int tid = threadIdx.x;
  const int w = tid>>6, lane = tid&63;
  const int wr = w>>1, wc = w&1;
  const int l16 = lane&15, l4 = lane>>4;
  const int bid = blockIdx.x;
  const int by = (bid&7)*4 + ((bid>>3)>>3);
  const int bx = (bid>>3)&7;
  const size_t m0 = (size_t)by*128, n0 = (size_t)bx*128;
  const int K = 1024;
  f32x4 acc[4][4];
  #pragma unroll
  for (int i=0;i<4;i++)
    #pragma unroll
    for (int j=0;j<4;j++) acc[i][j] = f32x4{0.f,0.f,0.f,0.f};

  GSTAGE(A, Bt, K, 0, 0);
  for (int t=0; t<16; ++t){
    __syncthreads();
    if (t < 15) GSTAGE(A, Bt, K, (t+1)*64, (t+1)&1);
    const char* Asb = smem + ((t&1)<<14);
    const char* Bsb = smem + 32768 + ((t&1)<<14);
    #pragma unroll
    for (int h2=0; h2<2; h2++){
      f16x8 af[4], bf[4];
      #pragma unroll
      for (int i=0;i<4;i++){
        int R = wr*64+i*16+l16;
        af[i] = *(const f16x8*)(Asb + R*128 + (((h2*4+l4)^(R&7))<<4));
      }
      #pragma unroll
      for (int j=0;j<4;j++){
        int R = wc*64+j*16+l16;
        bf[j] = *(const f16x8*)(Bsb + R*128 + (((h2*4+l4)^(R&7))<<4));
      }
      __builtin_amdgcn_s_setprio(1);
      #pragma unroll
      for (int i=0;i<4;i++)
        #pragma unroll
        for (int j=0;j<4;j++)
          acc[i][j] = __builtin_amdgcn_mfma_f32_16x16x32_f16(af[i], bf[j], acc[i][j], 0,0,0);
      __builtin_amdgcn_s_setprio(0);
    }
  }
  #pragma unroll
  for (int i=0;i<4;i++)
    #pragma unroll
    for (int j=0;j<4;j++)
      #pragma unroll
      for (int r=0;r<4;r++)
        C[(m0 + wr*64 + i*16 + l4*4 + r)*1024 + n0 + wc*64 + j*16 + l16] = acc[i][j][r];
}

// -------------------------------------------- pack ALL context K -> K' tiles
__launch_bounds__(256)
__global__ void pack_k_all(const float* __restrict__ lat, const float* __restrict__ txt,
                           const float* __restrict__ spk, char* __restrict__ Kt){
  int unit = blockIdx.x*16 + (threadIdx.x>>4);
  int ll = threadIdx.x & 15;
  int l = unit % 1280; int bh = unit / 1280;
  int b = bh >> 4, h = bh & 15;
  const float* src; int nL, li, l0;
  if (l < 256)      { src = lat; nL = 256; li = l;     l0 = 2048; }
  else if (l < 768) { src = txt; nL = 512; li = l-256; l0 = 2304; }
  else              { src = spk; nL = 512; li = l-768; l0 = 2816; }
  float4 v = *(const float4*)(src + (((size_t)b*nL + li)*16 + h)*64 + ll*4);
  uint2 o; o.x = pack2f16(v.x, v.y); o.y = pack2f16(v.z, v.w);
  int s = l0 + li; int tt = s >> 7, kl = s & 127;
  *(uint2*)(Kt + ((size_t)bh*NTILE + tt)*16384
               + (kl*8 + ((ll>>1) ^ (kl&7)))*16 + (ll&1)*8) = o;
}

// --------------------------- pack ALL context V -> V' tiles (sigma + bank XOR)
__launch_bounds__(256)
__global__ void pack_v_all(const float* __restrict__ lat, const float* __restrict__ txt,
                           const float* __restrict__ spk, char* __restrict__ Vt){
  __shared__ float t[128*68];
  const int bh = blockIdx.y, b = bh>>4, h = bh&15;
  const int tz = blockIdx.x;              // 0..9 -> storage tile 16+tz
  const float* src; int tl, nB;
  if (tz < 2)      { src = lat; tl = tz;   nB = 256; }
  else if (tz < 6) { src = txt; tl = tz-2; nB = 512; }
  else             { src = spk; tl = tz-6; nB = 512; }
  const float* sb = src + ((size_t)b*nB + tl*128)*1024 + h*64;
  const int tid = threadIdx.x;
  {
    int row = tid >> 1, half = tid & 1;
    #pragma unroll
    for (int i=0;i<8;i++){
      float4 v = *(const float4*)(sb + (size_t)row*1024 + half*32 + i*4);
      *(float4*)(&t[row*68 + half*32 + i*4]) = v;
    }
  }
  __syncthreads();
  char* dstb = Vt + ((size_t)bh*NTILE + 16 + tz)*16384;
  #pragma unroll
  for (int u=0;u<4;u++){
    int c = tid + u*256;
    int d = c >> 4;
    int vc = (c & 15) ^ (d & 7);
    int g = vc >> 1, hi = vc & 1;
    int kb_ = 32*(g>>1) + 16*(g&1) + 4*hi;
    uint4 o;
    o.x = pack2f16(t[(kb_+0)*68+d],  t[(kb_+1)*68+d]);
    o.y = pack2f16(t[(kb_+2)*68+d],  t[(kb_+3)*68+d]);
    o.z = pack2f16(t[(kb_+8)*68+d],  t[(kb_+9)*68+d]);
    o.w = pack2f16(t[(kb_+10)*68+d], t[(kb_+11)*68+d]);
    *(uint4*)(dstb + c*16) = o;
  }
}

// -------------------------------------------------------------- flash attention
// Split-K x2 (fixed-max softmax => partials add exactly). 64-key dbuf tiles.
// Dual interleaved QK^T chains (both 32-key sub-blocks' MFMAs issued together
// -> 2x MFMA issue parallelism, zero extra VALU), dual lsum chains, skip of
// fully-masked latent tiles. launch_bounds(256,3) gives the RA headroom for
// the second accumulator/fragment set without spilling (round-10 lesson).
__launch_bounds__(256, 3)
__global__ void attn_fwd(const f16* __restrict__ Qall, const char* __restrict__ Kt,
                         const char* __restrict__ Vt, const int* __restrict__ spp,
                         float* __restrict__ po, float* __restrict__ plsum){
  __shared__ __align__(16) char Ks[2][8192];
  __shared__ __align__(16) char Vs[2][8192];
  const int sp = *spp;
  const int tid = threadIdx.x, lane = tid & 63, w = tid >> 6;
  const int l31 = lane & 31, hi = lane >> 5, l7 = lane & 7;
  const int bid = blockIdx.x;
  const int bh = (bid&7)*4 + ((bid>>3)>>5);   // 128 blocks per XCD share 4 bh
  const int rem = (bid>>3)&31;
  const int qb = rem>>1, ksp = rem&1;
  const int b = bh >> 4, h = bh & 15;
  const int q0w = qb*128 + w*32;
  const f16*  Qb = Qall + (size_t)bh*SS*DD;
  const char* Kb = Kt + (size_t)bh*NTILE*16384;
  const char* Vb = Vt + (size_t)bh*NTILE*16384;

  // tile remap: skip fully-masked latent 64-key tiles (all in split 1: T=32..35)
  const int vl   = min(256, (sp + 3) >> 2);   // valid latent keys
  const int Ms   = 32 + ((vl + 63) >> 6);     // first fully-masked tile
  const int skip = 36 - Ms;                   // 0..4 tiles skipped
  const int nt   = ksp ? (26 - skip) : 26;
  #define TMAP(ti) (ksp ? ((26 + (ti)) < Ms ? (26 + (ti)) : (26 + (ti) + skip)) : (ti))

  f16x8 qf[4];
  {
    const f16* qrow = Qb + (size_t)(q0w + l31)*DD + hi*8;
    #pragma unroll
    for (int ks=0; ks<4; ks++) qf[ks] = *(const f16x8*)(qrow + ks*16);
  }

  f32x16 oA = {0,0,0,0,0,0,0,0,0,0,0,0,0,0,0,0};
  f32x16 oB = {0,0,0,0,0,0,0,0,0,0,0,0,0,0,0,0};
  float lsum0 = 0.f, lsum1 = 0.f;
  const h16x2 ones2 = {(__fp16)1.f, (__fp16)1.f};

  #define STAGE(bi, T) do { \
    const char* kb_ = Kb + (size_t)((T)>>1)*16384 + ((T)&1)*8192; \
    const char* vb_ = Vb + (size_t)((T)>>1)*16384 + ((T)&1)*128; \
    _Pragma("unroll") \
    for (int u=0; u<2; ++u){ \
      int c = tid + u*256; \
      __builtin_amdgcn_global_load_lds((gptr_t)(kb_ + c*16), (lptr_t)(&Ks[bi][c*16]), 16, 0, 0); \
      __builtin_amdgcn_global_load_lds((gptr_t)(vb_ + (size_t)(c>>3)*256 + (c&7)*16), \
                                       (lptr_t)(&Vs[bi][c*16]), 16, 0, 0); \
    } \
  } while(0)

  STAGE(0, TMAP(0));
  for (int ti = 0; ti < nt; ++ti){
    __syncthreads();
    if (ti < nt-1) STAGE((ti+1)&1, TMAP(ti+1));
    const char* Ksb = Ks[ti&1];
    const char* Vsb = Vs[ti&1];
    const int T = TMAP(ti);
    const bool maskt = (unsigned)(T-32) < 4u;   // latent 64-key tiles 32..35
    const int ktl = T*64 - 2048;

    // ---- dual interleaved QK^T: both 32-key sub-blocks at once
    f16x8 kf0[4], kf1[4];
    #pragma unroll
    for (int ks=0; ks<4; ks++){
      kf0[ks] = *(const f16x8*)(Ksb + (     l31)*128 + (((2*ks+hi) ^ l7))*16);
      kf1[ks] = *(const f16x8*)(Ksb + (32 + l31)*128 + (((2*ks+hi) ^ l7))*16);
    }
    f32x16 a0 = {0,0,0,0,0,0,0,0,0,0,0,0,0,0,0,0};
    f32x16 a1 = {0,0,0,0,0,0,0,0,0,0,0,0,0,0,0,0};
    __builtin_amdgcn_s_setprio(1);
    #pragma unroll
    for (int ks=0; ks<4; ks++){
      a0 = __builtin_amdgcn_mfma_f32_32x32x16_f16(kf0[ks], qf[ks], a0, 0,0,0);
      a1 = __builtin_amdgcn_mfma_f32_32x32x16_f16(kf1[ks], qf[ks], a1, 0,0,0);
    }
    __builtin_amdgcn_s_setprio(0);

    #pragma unroll
    for (int kb=0; kb<2; ++kb){
      f32x16 acc = kb ? a1 : a0;
      if (maskt){
        #pragma unroll
        for (int r=0;r<16;r++){
          int kk = ktl + kb*32 + (r&3) + 8*(r>>2) + 4*hi;
          if (kk*4 >= sp) acc[r] = -1e5f;
        }
      }
      // fixed-max softmax: p = 2^s (bounded by 2^11.54 < f16 max).
      // pkrtz packs the pair in 1 instr; fdot2 with ones accumulates lsum
      // from the SAME rounded f16 values that feed PV. Two lsum chains (ILP).
      uint32_t pk[8];
      #pragma unroll
      for (int i=0;i<8;i++){
        float p0 = __builtin_amdgcn_exp2f(acc[2*i]);
        float p1 = __builtin_amdgcn_exp2f(acc[2*i+1]);
        h16x2 h2 = __builtin_amdgcn_cvt_pkrtz(p0, p1);
#if __has_builtin(__builtin_amdgcn_fdot2)
        if (i & 1) lsum1 = __builtin_amdgcn_fdot2(h2, ones2, lsum1, false);
        else       lsum0 = __builtin_amdgcn_fdot2(h2, ones2, lsum0, false);
#else
        if (i & 1) lsum1 += (float)h2[0] + (float)h2[1];
        else       lsum0 += (float)h2[0] + (float)h2[1];
#endif
        union { h16x2 v; uint32_t u; } cv; cv.v = h2; pk[i] = cv.u;
      }
      __builtin_amdgcn_s_setprio(1);
      #pragma unroll
      for (int gg=0; gg<2; gg++){
        union { uint4 u; f16x8 v; } pa;
        pa.u = make_uint4(pk[4*gg], pk[4*gg+1], pk[4*gg+2], pk[4*gg+3]);
        int cofs = ((2*(2*kb+gg) + hi) ^ l7)*16;
        f16x8 v0 = *(const f16x8*)(Vsb + l31*128 + cofs);
        f16x8 v1 = *(const f16x8*)(Vsb + (32+l31)*128 + cofs);
        oA = __builtin_amdgcn_mfma_f32_32x32x16_f16(pa.v, v0, oA, 0,0,0);
        oB = __builtin_amdgcn_mfma_f32_32x32x16_f16(pa.v, v1, oB, 0,0,0);
      }
      __builtin_amdgcn_s_setprio(0);
    }
  }
  #undef STAGE
  #undef TMAP

  float lsum = lsum0 + lsum1;
  lsum += __shfl_xor(lsum, 32, 64);
  float* pob = po + (size_t)ksp*NT*1024;
  #pragma unroll
  for (int r=0;r<16;r++){
    int qo = (r&3) + 8*(r>>2) + 4*hi;
    size_t token = (size_t)(b*SS + q0w + qo);
    pob[token*1024 + h*64 + l31]      = oA[r];
    pob[token*1024 + h*64 + 32 + l31] = oB[r];
  }
  if (hi == 0){
    size_t token = (size_t)(b*SS + q0w + l31);
    plsum[(size_t)ksp*NT*HH + token*HH + h] = lsum;
  }
}

// ------------------------------------ combine: (o0+o1)/(l0+l1) * sigma(gate)
__launch_bounds__(256)
__global__ void attn_combine(const float* __restrict__ po, const float* __restrict__ plsum,
                             const f16* __restrict__ gateS, f16* __restrict__ go){
  int idx = blockIdx.x*256 + threadIdx.x;   // NT*256 threads, 4 cols each
  int token = idx >> 8;
  int col = (idx & 255)*4;
  int h = col >> 6;
  float4 p0 = *(const float4*)(po + (size_t)token*1024 + col);
  float4 p1 = *(const float4*)(po + (size_t)NT*1024 + (size_t)token*1024 + col);
  float ls = plsum[(size_t)token*HH + h] + plsum[(size_t)NT*HH + (size_t)token*HH + h];
  float inv = 1.f / ls;
  const f16* gp = gateS + (size_t)token*1024 + col;
  float g0 = (float)gp[0], g1 = (float)gp[1], g2 = (float)gp[2], g3 = (float)gp[3];
  uint2 o;
  o.x = pack2f16((p0.x+p1.x)*inv*g0, (p0.y+p1.y)*inv*g1);
  o.y = pack2f16((p0.z+p1.z)*inv*g2, (p0.w+p1.w)*inv*g3);
  *(uint2*)(go + (size_t)token*1024 + col) = o;
}

// ---------------------------------------------------------------------- launch
extern "C" void kernel_launch(void* const* d_in, const int* in_sizes, int n_in,
                              void* d_out, int out_size, void* d_ws, size_t ws_size,
                              hipStream_t stream){
  const float* x        = (const float*)d_in[0];
  const float* fcos     = (const float*)d_in[3];
  const float* fsin     = (const float*)d_in[4];
  const float* kv_txt_k = (const float*)d_in[5];
  const float* kv_txt_v = (const float*)d_in[6];
  const float* kv_spk_k = (const float*)d_in[7];
  const float* kv_spk_v = (const float*)d_in[8];
  const float* kv_lat_k = (const float*)d_in[9];
  const float* kv_lat_v = (const float*)d_in[10];
  const int*   sp       = (const int*)d_in[11];
  const float* wq       = (const float*)d_in[12];
  const float* wk       = (const float*)d_in[13];
  const float* wv       = (const float*)d_in[14];
  const float* gw       = (const float*)d_in[15];
  const float* wo       = (const float*)d_in[16];
  const float* qnw      = (const float*)d_in[17];
  const float* knw      = (const float*)d_in[18];
  float* out = (float*)d_out;
  char* ws = (char*)d_ws;

  f16*   xh     = (f16*)  (ws + 0);          // 8 MB
  f16*   WtQKVG = (f16*)  (ws + 8388608);    // 8 MB
  f16*   WtO    = (f16*)  (ws + 16777216);   // 2 MB
  f16*   gateS  = (f16*)  (ws + 18874368);   // 8 MB  f16 sigma(gate)
  f16*   Qall   = (f16*)  (ws + 27262976);   // 8 MB  (B,H,S,D)
  char*  Kt     = (char*) (ws + 35651584);   // 13.6 MB K' tiles
  char*  Vt     = (char*) (ws + 49283072);   // 13.6 MB V' tiles
  f16*   go     = (f16*)  (ws + 62914560);   // 8 MB
  float* po     = (float*)(ws + 71303168);   // 32 MB partial O (2 splits)
  float* plsum  = (float*)(ws + 104857600);  // 512 KB partial lsum

  cvt_f32_f16<<<4096, 256, 0, stream>>>(x, xh, (size_t)NT*1024);
  dim3 tb(32,8);
  transpose_cvt5<<<dim3(32,32,5), tb, 0, stream>>>(wq, wk, wv, gw, wo, WtQKVG, WtO);

  gemm_qkvg<<<1024, 256, 0, stream>>>(xh, WtQKVG, qnw, knw, fcos, fsin, sp,
                                      Qall, Kt, Vt, gateS);

  pack_k_all<<<2560, 256, 0, stream>>>(kv_lat_k, kv_txt_k, kv_spk_k, Kt);
  pack_v_all<<<dim3(10,32), 256, 0, stream>>>(kv_lat_v, kv_txt_v, kv_spk_v, Vt);

  attn_fwd<<<1024, 256, 0, stream>>>(Qall, Kt, Vt, sp, po, plsum);
  attn_combine<<<4096, 256, 0, stream>>>(po, plsum, gateS, go);

  gemm_out<<<256, 256, 0, stream>>>(go, WtO, out);
}

// Round 14
// 156.951 us; speedup vs baseline: 1.1226x; 1.1085x over previous
//
#include <hip/hip_runtime.h>
#include <cstdint>
#include <cstddef>

typedef _Float16 f16;
typedef __attribute__((ext_vector_type(2))) __fp16 h16x2;   // builtin cvt_pkrtz/fdot2 type
typedef __attribute__((ext_vector_type(8))) _Float16 f16x8;
typedef __attribute__((ext_vector_type(4))) float f32x4;
typedef __attribute__((ext_vector_type(16))) float f32x16;
typedef const __attribute__((address_space(1))) uint32_t* gptr_t;
typedef __attribute__((address_space(3))) uint32_t* lptr_t;

#define DEV __device__ __forceinline__

DEV uint32_t pack2f16(float a, float b){
  union { f16 h[2]; uint32_t u; } p;
  p.h[0] = (f16)a; p.h[1] = (f16)b; return p.u;
}
DEV uint32_t cat2(f16 a, f16 b){
  union { f16 h[2]; uint32_t u; } p;
  p.h[0] = a; p.h[1] = b; return p.u;
}

// ---- problem constants
#define BB 2
#define SS 2048
#define HH 16
#define DD 64
#define NT (BB*SS)       // 4096 tokens
#define LLAT 256
#define LTOT 3328        // 2048 + 256 + 512 + 512
#define NTILE 26         // 3328 / 128 (128-key storage tiles)
#define LOG2E 1.44269504f
#define SC2 (0.125f*LOG2E)

// K' tile (per bh, per 128-key tile, 16KB): 16B chunk (key, dc) holds d=dc*8..+7,
//   at linear chunk pos key*8 + (dc ^ (key&7)).
// V' tile (16KB): 16B chunk (d, vc) holds PV k-slots s = vc*8+e; slot
//   s=16g+8hi+e -> key 32*(g>>1)+16*(g&1)+8*(e>>2)+4*hi+(e&3); chunk at
//   linear pos d*16 + (vc ^ (d&7)).
// Epilogue LDS transpose buffer Kl[128 keys][128 cols] f16, chunk-XOR'd:
#define KLIDX(key,col) (((key)<<7) + (((((col)>>3)^((key)&15)))<<3) + ((col)&7))

// ---------------------------------------------------------------- cvt f32->f16
__global__ void cvt_f32_f16(const float* __restrict__ src, f16* __restrict__ dst, size_t n){
  size_t i = ((size_t)blockIdx.x*blockDim.x + threadIdx.x)*4;
  if (i >= n) return;
  float4 v = *(const float4*)(src + i);
  uint2 o; o.x = pack2f16(v.x, v.y); o.y = pack2f16(v.z, v.w);
  *(uint2*)(dst + i) = o;
}

// ------------------------------- 5 weight transposes in one launch (z picks src)
__global__ void transpose_cvt5(const float* __restrict__ w0, const float* __restrict__ w1,
                               const float* __restrict__ w2, const float* __restrict__ w3,
                               const float* __restrict__ w4,
                               f16* __restrict__ dqkvg, f16* __restrict__ dout){
  __shared__ float t[32][33];
  int z = blockIdx.z;
  const float* src = z==0 ? w0 : z==1 ? w1 : z==2 ? w2 : z==3 ? w3 : w4;
  f16* dst = (z<4) ? (dqkvg + ((size_t)z<<20)) : dout;
  int tx = threadIdx.x, ty = threadIdx.y;
  int bx = blockIdx.x, by = blockIdx.y;
  #pragma unroll
  for (int i=0;i<4;i++){
    int r = ty + i*8;
    t[r][tx] = src[(size_t)(by*32 + r)*1024 + bx*32 + tx];
  }
  __syncthreads();
  #pragma unroll
  for (int i=0;i<4;i++){
    int r = ty + i*8;
    dst[(size_t)(bx*32 + r)*1024 + by*32 + tx] = (f16)t[tx][r];
  }
}

// GEMM staging (double-buffered, 64KB): row-major LDS rows of 128B, chunk pc
// within a row holds source k-chunk kc = pc ^ (row&7) (pre-swizzled source,
// linear GLDS dest). Coalesced: 8 lanes cover a full 128B row.
#define GSTAGE(Aptr, Bptr, Kd, ktv, bb) do { \
  char* Asb_ = smem + ((bb)<<14); \
  char* Bsb_ = smem + 32768 + ((bb)<<14); \
  _Pragma("unroll") \
  for (int u=0; u<4; ++u){ \
    int c = tid + u*256; \
    int row = c>>3, kc = (c&7) ^ (row&7); \
    __builtin_amdgcn_global_load_lds((gptr_t)((Aptr) + (m0+row)*(Kd) + (ktv) + kc*8), \
                                     (lptr_t)(Asb_ + c*16), 16, 0, 0); \
    __builtin_amdgcn_global_load_lds((gptr_t)((Bptr) + (n0+row)*(Kd) + (ktv) + kc*8), \
                                     (lptr_t)(Bsb_ + c*16), 16, 0, 0); \
  } \
} while(0)

// --------------------------------------------------------- fused QKVG GEMM
// [4096 x 4096] = x @ [wq|wk|wv|gw]. Double-buffered, 1 barrier/K-step.
// Epilogue fused per column region: q/k RMS+RoPE+pack, v -> V' tiles (sigma),
// gate -> sigmoid. All global writes coalesced 16B.
__launch_bounds__(256, 2)
__global__ void gemm_qkvg(const f16* __restrict__ A, const f16* __restrict__ Bt,
                          const float* __restrict__ qnw, const float* __restrict__ knw,
                          const float* __restrict__ fcos, const float* __restrict__ fsin,
                          const int* __restrict__ spp,
                          f16* __restrict__ Qall, char* __restrict__ Kt,
                          char* __restrict__ Vt, f16* __restrict__ gateS){
  __shared__ __align__(16) char smem[65536];
  const int tid = threadIdx.x;
  const int w = tid>>6, lane = tid&63;
  const int wr = w>>1, wc = w&1;
  const int l16 = lane&15, l4 = lane>>4;
  const int bid = blockIdx.x;
  const int x = bid&7, r_ = bid>>3;
  const int by = (x>>2)*16 + (r_>>3);
  const int bx = (x&3)*8 + (r_&7);
  const size_t m0 = (size_t)by*128, n0 = (size_t)bx*128;
  const int K = 1024;
  f32x4 acc[4][4];
  #pragma unroll
  for (int i=0;i<4;i++)
    #pragma unroll
    for (int j=0;j<4;j++) acc[i][j] = f32x4{0.f,0.f,0.f,0.f};

  GSTAGE(A, Bt, K, 0, 0);
  for (int t=0; t<16; ++t){
    __syncthreads();                       // drains STAGE(t)
    if (t < 15) GSTAGE(A, Bt, K, (t+1)*64, (t+1)&1);
    const char* Asb = smem + ((t&1)<<14);
    const char* Bsb = smem + 32768 + ((t&1)<<14);
    #pragma unroll
    for (int h2=0; h2<2; h2++){
      f16x8 af[4], bf[4];
      #pragma unroll
      for (int i=0;i<4;i++){
        int R = wr*64+i*16+l16;
        af[i] = *(const f16x8*)(Asb + R*128 + (((h2*4+l4)^(R&7))<<4));
      }
      #pragma unroll
      for (int j=0;j<4;j++){
        int R = wc*64+j*16+l16;
        bf[j] = *(const f16x8*)(Bsb + R*128 + (((h2*4+l4)^(R&7))<<4));
      }
      __builtin_amdgcn_s_setprio(1);
      #pragma unroll
      for (int i=0;i<4;i++)
        #pragma unroll
        for (int j=0;j<4;j++)
          acc[i][j] = __builtin_amdgcn_mfma_f32_16x16x32_f16(af[i], bf[j], acc[i][j], 0,0,0);
      __builtin_amdgcn_s_setprio(0);
    }
  }

  // ----------------------------- epilogue
  const int region = bx >> 3;           // 0 q, 1 k, 2 v, 3 gate
  const int s0 = (int)(m0 & 2047);
  const int b_ = (int)(m0 >> 11);
  const int tt = s0 >> 7;
  f16* Kl = (f16*)smem;                 // 32KB transpose buffer (reuse)
  __syncthreads();                      // all LDS tile reads done

  if (region <= 1){
    const int sp = *spp;
    const int h = (bx&7)*2 + wc;
    const float* wnorm = (region==0 ? qnw : knw) + h*64;
    const float wsc = (region==0) ? SC2 : 1.f;
    const bool do_rope = h < 8;
    #pragma unroll
    for (int i=0;i<4;i++){
      float s2[4];
      #pragma unroll
      for (int r=0;r<4;r++)
        s2[r] = acc[i][0][r]*acc[i][0][r] + acc[i][1][r]*acc[i][1][r]
              + acc[i][2][r]*acc[i][2][r] + acc[i][3][r]*acc[i][3][r];
      #pragma unroll
      for (int msk=1; msk<16; msk<<=1)
        #pragma unroll
        for (int r=0;r<4;r++) s2[r] += __shfl_xor(s2[r], msk, 64);
      float rsq[4];
      #pragma unroll
      for (int r=0;r<4;r++) rsq[r] = rsqrtf(s2[r]*(1.f/64.f) + 1e-5f) * wsc;
      #pragma unroll
      for (int j=0;j<4;j++){
        const int chd = j*16 + l16;
        const float wn = wnorm[chd];
        float v_[4];
        #pragma unroll
        for (int r=0;r<4;r++) v_[r] = acc[i][j][r]*rsq[r]*wn;
        if (do_rope){
          const float sgn = (l16&1) ? 1.f : -1.f;
          #pragma unroll
          for (int r=0;r<4;r++){
            int s_ = s0 + wr*64 + i*16 + l4*4 + r;
            float c_ = fcos[(size_t)(sp+s_)*32 + j*8 + (l16>>1)];
            float sn = fsin[(size_t)(sp+s_)*32 + j*8 + (l16>>1)];
            float pr = __shfl_xor(v_[r], 1, 64);
            v_[r] = v_[r]*c_ + sgn*pr*sn;
          }
        }
        #pragma unroll
        for (int r=0;r<4;r++){
          int key = wr*64 + i*16 + l4*4 + r;
          Kl[KLIDX(key, wc*64 + chd)] = (f16)v_[r];
        }
      }
    }
    __syncthreads();
    #pragma unroll
    for (int u=0;u<8;u++){
      int cc = tid + u*256;
      int h_loc = cc>>10, cl = cc&1023;
      int key = cl>>3, pc = cl&7;
      size_t bh2 = (size_t)(b_*16 + (bx&7)*2 + h_loc);
      if (region==0){
        f16x8 vv = *(const f16x8*)(Kl + KLIDX(key, h_loc*64 + pc*8));
        *(f16x8*)(Qall + (bh2*SS + s0 + key)*64 + pc*8) = vv;
      } else {
        int dc = pc ^ (key&7);
        f16x8 vv = *(const f16x8*)(Kl + KLIDX(key, h_loc*64 + dc*8));
        *(f16x8*)(Kt + (bh2*NTILE + tt)*16384 + (size_t)cl*16) = vv;
      }
    }
  } else if (region == 2){
    #pragma unroll
    for (int i=0;i<4;i++)
      #pragma unroll
      for (int j=0;j<4;j++)
        #pragma unroll
        for (int r=0;r<4;r++){
          int key = wr*64 + i*16 + l4*4 + r;
          Kl[KLIDX(key, wc*64 + j*16 + l16)] = (f16)acc[i][j][r];
        }
    __syncthreads();
    #pragma unroll
    for (int u=0;u<8;u++){
      int cc = tid + u*256;
      int h_loc = cc>>10, c = cc&1023;
      int d = c>>4, vc = (c&15)^(d&7);
      int g = vc>>1, hi2 = vc&1;
      int kb_ = 32*(g>>1) + 16*(g&1) + 4*hi2;
      int col = h_loc*64 + d;
      f16 a0 = Kl[KLIDX(kb_+0,col)],  a1 = Kl[KLIDX(kb_+1,col)];
      f16 a2 = Kl[KLIDX(kb_+2,col)],  a3 = Kl[KLIDX(kb_+3,col)];
      f16 a4 = Kl[KLIDX(kb_+8,col)],  a5 = Kl[KLIDX(kb_+9,col)];
      f16 a6 = Kl[KLIDX(kb_+10,col)], a7 = Kl[KLIDX(kb_+11,col)];
      uint4 o; o.x = cat2(a0,a1); o.y = cat2(a2,a3); o.z = cat2(a4,a5); o.w = cat2(a6,a7);
      size_t bh2 = (size_t)(b_*16 + (bx&7)*2 + h_loc);
      *(uint4*)(Vt + (bh2*NTILE + tt)*16384 + (size_t)c*16) = o;
    }
  } else {
    #pragma unroll
    for (int i=0;i<4;i++)
      #pragma unroll
      for (int j=0;j<4;j++)
        #pragma unroll
        for (int r=0;r<4;r++){
          int key = wr*64 + i*16 + l4*4 + r;
          float v_ = 1.f/(1.f + __builtin_amdgcn_exp2f(-acc[i][j][r]*LOG2E));
          Kl[KLIDX(key, wc*64 + j*16 + l16)] = (f16)v_;
        }
    __syncthreads();
    #pragma unroll
    for (int u=0;u<8;u++){
      int cc = tid + u*256;
      int key = cc>>4, ch = cc&15;
      f16x8 vv = *(const f16x8*)(Kl + KLIDX(key, ch*8));
      *(f16x8*)(gateS + (size_t)(m0 + key)*1024 + (bx&7)*128 + ch*8) = vv;
    }
  }
}

// ----------------------------------------------- final projection GEMM (f32 C)
__launch_bounds__(256, 2)
__global__ void gemm_out(const f16* __restrict__ A, const f16* __restrict__ Bt,
                         float* __restrict__ C){
  __shared__ __align__(16) char smem[65536];
  const int tid = threadIdx.x;
  const int w = tid>>6, lane = tid&63;
  const int wr = w>>1, wc = w&1;
  const int l16 = lane&15, l4 = lane>>4;
  const int bid = blockIdx.x;
  const int by = (bid&7)*4 + ((bid>>3)>>3);
  const int bx = (bid>>3)&7;
  const size_t m0 = (size_t)by*128, n0 = (size_t)bx*128;
  const int K = 1024;
  f32x4 acc[4][4];
  #pragma unroll
  for (int i=0;i<4;i++)
    #pragma unroll
    for (int j=0;j<4;j++) acc[i][j] = f32x4{0.f,0.f,0.f,0.f};

  GSTAGE(A, Bt, K, 0, 0);
  for (int t=0; t<16; ++t){
    __syncthreads();
    if (t < 15) GSTAGE(A, Bt, K, (t+1)*64, (t+1)&1);
    const char* Asb = smem + ((t&1)<<14);
    const char* Bsb = smem + 32768 + ((t&1)<<14);
    #pragma unroll
    for (int h2=0; h2<2; h2++){
      f16x8 af[4], bf[4];
      #pragma unroll
      for (int i=0;i<4;i++){
        int R = wr*64+i*16+l16;
        af[i] = *(const f16x8*)(Asb + R*128 + (((h2*4+l4)^(R&7))<<4));
      }
      #pragma unroll
      for (int j=0;j<4;j++){
        int R = wc*64+j*16+l16;
        bf[j] = *(const f16x8*)(Bsb + R*128 + (((h2*4+l4)^(R&7))<<4));
      }
      __builtin_amdgcn_s_setprio(1);
      #pragma unroll
      for (int i=0;i<4;i++)
        #pragma unroll
        for (int j=0;j<4;j++)
          acc[i][j] = __builtin_amdgcn_mfma_f32_16x16x32_f16(af[i], bf[j], acc[i][j], 0,0,0);
      __builtin_amdgcn_s_setprio(0);
    }
  }
  #pragma unroll
  for (int i=0;i<4;i++)
    #pragma unroll
    for (int j=0;j<4;j++)
      #pragma unroll
      for (int r=0;r<4;r++)
        C[(m0 + wr*64 + i*16 + l4*4 + r)*1024 + n0 + wc*64 + j*16 + l16] = acc[i][j][r];
}

// -------------------------------------------- pack ALL context K -> K' tiles
__launch_bounds__(256)
__global__ void pack_k_all(const float* __restrict__ lat, const float* __restrict__ txt,
                           const float* __restrict__ spk, char* __restrict__ Kt){
  int unit = blockIdx.x*16 + (threadIdx.x>>4);
  int ll = threadIdx.x & 15;
  int l = unit % 1280; int bh = unit / 1280;
  int b = bh >> 4, h = bh & 15;
  const float* src; int nL, li, l0;
  if (l < 256)      { src = lat; nL = 256; li = l;     l0 = 2048; }
  else if (l < 768) { src = txt; nL = 512; li = l-256; l0 = 2304; }
  else              { src = spk; nL = 512; li = l-768; l0 = 2816; }
  float4 v = *(const float4*)(src + (((size_t)b*nL + li)*16 + h)*64 + ll*4);
  uint2 o; o.x = pack2f16(v.x, v.y); o.y = pack2f16(v.z, v.w);
  int s = l0 + li; int tt = s >> 7, kl = s & 127;
  *(uint2*)(Kt + ((size_t)bh*NTILE + tt)*16384
               + (kl*8 + ((ll>>1) ^ (kl&7)))*16 + (ll&1)*8) = o;
}

// --------------------------- pack ALL context V -> V' tiles (sigma + bank XOR)
__launch_bounds__(256)
__global__ void pack_v_all(const float* __restrict__ lat, const float* __restrict__ txt,
                           const float* __restrict__ spk, char* __restrict__ Vt){
  __shared__ float t[128*68];
  const int bh = blockIdx.y, b = bh>>4, h = bh&15;
  const int tz = blockIdx.x;              // 0..9 -> storage tile 16+tz
  const float* src; int tl, nB;
  if (tz < 2)      { src = lat; tl = tz;   nB = 256; }
  else if (tz < 6) { src = txt; tl = tz-2; nB = 512; }
  else             { src = spk; tl = tz-6; nB = 512; }
  const float* sb = src + ((size_t)b*nB + tl*128)*1024 + h*64;
  const int tid = threadIdx.x;
  {
    int row = tid >> 1, half = tid & 1;
    #pragma unroll
    for (int i=0;i<8;i++){
      float4 v = *(const float4*)(sb + (size_t)row*1024 + half*32 + i*4);
      *(float4*)(&t[row*68 + half*32 + i*4]) = v;
    }
  }
  __syncthreads();
  char* dstb = Vt + ((size_t)bh*NTILE + 16 + tz)*16384;
  #pragma unroll
  for (int u=0;u<4;u++){
    int c = tid + u*256;
    int d = c >> 4;
    int vc = (c & 15) ^ (d & 7);
    int g = vc >> 1, hi = vc & 1;
    int kb_ = 32*(g>>1) + 16*(g&1) + 4*hi;
    uint4 o;
    o.x = pack2f16(t[(kb_+0)*68+d],  t[(kb_+1)*68+d]);
    o.y = pack2f16(t[(kb_+2)*68+d],  t[(kb_+3)*68+d]);
    o.z = pack2f16(t[(kb_+8)*68+d],  t[(kb_+9)*68+d]);
    o.w = pack2f16(t[(kb_+10)*68+d], t[(kb_+11)*68+d]);
    *(uint4*)(dstb + c*16) = o;
  }
}

// -------------------------------------------------------------- flash attention
// NON-SPLIT (one block owns all 52 64-key tiles; no po/combine round-trip).
// Fixed-max softmax (p = 2^s exact-bounded), pkrtz pack + fdot2 dual-lsum,
// fully-masked latent tiles skipped, gate fused into the f16 epilogue.
__launch_bounds__(256, 4)
__global__ void attn_fwd(const f16* __restrict__ Qall, const char* __restrict__ Kt,
                         const char* __restrict__ Vt, const int* __restrict__ spp,
                         const f16* __restrict__ gateS, f16* __restrict__ go){
  __shared__ __align__(16) char Ks[2][8192];
  __shared__ __align__(16) char Vs[2][8192];
  const int sp = *spp;
  const int tid = threadIdx.x, lane = tid & 63, w = tid >> 6;
  const int l31 = lane & 31, hi = lane >> 5, l7 = lane & 7;
  const int bid = blockIdx.x;
  const int bh = (bid&7)*4 + ((bid>>3)>>4);   // 64 blocks per XCD share 4 bh
  const int qb = (bid>>3) & 15;
  const int b = bh >> 4, h = bh & 15;
  const int q0w = qb*128 + w*32;
  const f16*  Qb = Qall + (size_t)bh*SS*DD;
  const char* Kb = Kt + (size_t)bh*NTILE*16384;
  const char* Vb = Vt + (size_t)bh*NTILE*16384;

  // 64-key tiles 0..51; latent = 32..35. Skip fully-masked ones.
  const int vl   = min(256, (sp + 3) >> 2);   // valid latent keys
  const int Ms   = 32 + ((vl + 63) >> 6);     // first fully-masked tile (32..36)
  const int skip = 36 - Ms;                   // 0..4 tiles skipped
  const int nt   = 52 - skip;
  #define TMAP(ti) ((ti) < Ms ? (ti) : (ti) + skip)

  f16x8 qf[4];
  {
    const f16* qrow = Qb + (size_t)(q0w + l31)*DD + hi*8;
    #pragma unroll
    for (int ks=0; ks<4; ks++) qf[ks] = *(const f16x8*)(qrow + ks*16);
  }

  f32x16 oA = {0,0,0,0,0,0,0,0,0,0,0,0,0,0,0,0};
  f32x16 oB = {0,0,0,0,0,0,0,0,0,0,0,0,0,0,0,0};
  float lsum0 = 0.f, lsum1 = 0.f;
  const h16x2 ones2 = {(__fp16)1.f, (__fp16)1.f};

  #define STAGE(bi, T) do { \
    const char* kb_ = Kb + (size_t)((T)>>1)*16384 + ((T)&1)*8192; \
    const char* vb_ = Vb + (size_t)((T)>>1)*16384 + ((T)&1)*128; \
    _Pragma("unroll") \
    for (int u=0; u<2; ++u){ \
      int c = tid + u*256; \
      __builtin_amdgcn_global_load_lds((gptr_t)(kb_ + c*16), (lptr_t)(&Ks[bi][c*16]), 16, 0, 0); \
      __builtin_amdgcn_global_load_lds((gptr_t)(vb_ + (size_t)(c>>3)*256 + (c&7)*16), \
                                       (lptr_t)(&Vs[bi][c*16]), 16, 0, 0); \
    } \
  } while(0)

  STAGE(0, TMAP(0));
  for (int ti = 0; ti < nt; ++ti){
    __syncthreads();
    if (ti < nt-1) STAGE((ti+1)&1, TMAP(ti+1));
    const char* Ksb = Ks[ti&1];
    const char* Vsb = Vs[ti&1];
    const int T = TMAP(ti);
    const bool maskt = (unsigned)(T-32) < 4u;   // latent 64-key tiles 32..35
    const int ktl = T*64 - 2048;
    #pragma unroll
    for (int kb=0; kb<2; ++kb){
      f16x8 kf[4];
      #pragma unroll
      for (int ks=0; ks<4; ks++)
        kf[ks] = *(const f16x8*)(Ksb + (32*kb + l31)*128 + (((2*ks+hi) ^ l7))*16);
      f32x16 acc = {0,0,0,0,0,0,0,0,0,0,0,0,0,0,0,0};
      __builtin_amdgcn_s_setprio(1);
      #pragma unroll
      for (int ks=0; ks<4; ks++)
        acc = __builtin_amdgcn_mfma_f32_32x32x16_f16(kf[ks], qf[ks], acc, 0,0,0);
      __builtin_amdgcn_s_setprio(0);
      if (maskt){
        #pragma unroll
        for (int r=0;r<16;r++){
          int kk = ktl + kb*32 + (r&3) + 8*(r>>2) + 4*hi;
          if (kk*4 >= sp) acc[r] = -1e5f;
        }
      }
      // fixed-max softmax: p = 2^s (bounded by 2^11.54 < f16 max).
      // pkrtz packs the pair in 1 instr; fdot2 with ones accumulates lsum
      // from the SAME rounded f16 values that feed PV. Two lsum chains (ILP).
      uint32_t pk[8];
      #pragma unroll
      for (int i=0;i<8;i++){
        float p0 = __builtin_amdgcn_exp2f(acc[2*i]);
        float p1 = __builtin_amdgcn_exp2f(acc[2*i+1]);
        h16x2 h2 = __builtin_amdgcn_cvt_pkrtz(p0, p1);
#if __has_builtin(__builtin_amdgcn_fdot2)
        if (i & 1) lsum1 = __builtin_amdgcn_fdot2(h2, ones2, lsum1, false);
        else       lsum0 = __builtin_amdgcn_fdot2(h2, ones2, lsum0, false);
#else
        if (i & 1) lsum1 += (float)h2[0] + (float)h2[1];
        else       lsum0 += (float)h2[0] + (float)h2[1];
#endif
        union { h16x2 v; uint32_t u; } cv; cv.v = h2; pk[i] = cv.u;
      }
      __builtin_amdgcn_s_setprio(1);
      #pragma unroll
      for (int gg=0; gg<2; gg++){
        union { uint4 u; f16x8 v; } pa;
        pa.u = make_uint4(pk[4*gg], pk[4*gg+1], pk[4*gg+2], pk[4*gg+3]);
        int cofs = ((2*(2*kb+gg) + hi) ^ l7)*16;
        f16x8 v0 = *(const f16x8*)(Vsb + l31*128 + cofs);
        f16x8 v1 = *(const f16x8*)(Vsb + (32+l31)*128 + cofs);
        oA = __builtin_amdgcn_mfma_f32_32x32x16_f16(pa.v, v0, oA, 0,0,0);
        oB = __builtin_amdgcn_mfma_f32_32x32x16_f16(pa.v, v1, oB, 0,0,0);
      }
      __builtin_amdgcn_s_setprio(0);
    }
  }
  #undef STAGE
  #undef TMAP

  float lsum = lsum0 + lsum1;
  lsum += __shfl_xor(lsum, 32, 64);
  float linv = 1.f / lsum;
  #pragma unroll
  for (int r=0;r<16;r++){
    int qo = (r&3) + 8*(r>>2) + 4*hi;
    float nv = __shfl(linv, qo, 64);
    size_t token = (size_t)(b*SS + q0w + qo);
    const f16* gr = gateS + token*1024 + h*64;
    float s0_ = (float)gr[l31], s1_ = (float)gr[32 + l31];
    f16* orow = go + token*1024 + h*64;
    orow[l31]      = (f16)(oA[r]*nv*s0_);
    orow[32 + l31] = (f16)(oB[r]*nv*s1_);
  }
}

// ---------------------------------------------------------------------- launch
extern "C" void kernel_launch(void* const* d_in, const int* in_sizes, int n_in,
                              void* d_out, int out_size, void* d_ws, size_t ws_size,
                              hipStream_t stream){
  const float* x        = (const float*)d_in[0];
  const float* fcos     = (const float*)d_in[3];
  const float* fsin     = (const float*)d_in[4];
  const float* kv_txt_k = (const float*)d_in[5];
  const float* kv_txt_v = (const float*)d_in[6];
  const float* kv_spk_k = (const float*)d_in[7];
  const float* kv_spk_v = (const float*)d_in[8];
  const float* kv_lat_k = (const float*)d_in[9];
  const float* kv_lat_v = (const float*)d_in[10];
  const int*   sp       = (const int*)d_in[11];
  const float* wq       = (const float*)d_in[12];
  const float* wk       = (const float*)d_in[13];
  const float* wv       = (const float*)d_in[14];
  const float* gw       = (const float*)d_in[15];
  const float* wo       = (const float*)d_in[16];
  const float* qnw      = (const float*)d_in[17];
  const float* knw      = (const float*)d_in[18];
  float* out = (float*)d_out;
  char* ws = (char*)d_ws;

  f16*   xh     = (f16*)  (ws + 0);          // 8 MB
  f16*   WtQKVG = (f16*)  (ws + 8388608);    // 8 MB
  f16*   WtO    = (f16*)  (ws + 16777216);   // 2 MB
  f16*   gateS  = (f16*)  (ws + 18874368);   // 8 MB  f16 sigma(gate)
  f16*   Qall   = (f16*)  (ws + 27262976);   // 8 MB  (B,H,S,D)
  char*  Kt     = (char*) (ws + 35651584);   // 13.6 MB K' tiles
  char*  Vt     = (char*) (ws + 49283072);   // 13.6 MB V' tiles
  f16*   go     = (f16*)  (ws + 62914560);   // 8 MB

  cvt_f32_f16<<<4096, 256, 0, stream>>>(x, xh, (size_t)NT*1024);
  dim3 tb(32,8);
  transpose_cvt5<<<dim3(32,32,5), tb, 0, stream>>>(wq, wk, wv, gw, wo, WtQKVG, WtO);

  gemm_qkvg<<<1024, 256, 0, stream>>>(xh, WtQKVG, qnw, knw, fcos, fsin, sp,
                                      Qall, Kt, Vt, gateS);

  pack_k_all<<<2560, 256, 0, stream>>>(kv_lat_k, kv_txt_k, kv_spk_k, Kt);
  pack_v_all<<<dim3(10,32), 256, 0, stream>>>(kv_lat_v, kv_txt_v, kv_spk_v, Vt);

  attn_fwd<<<512, 256, 0, stream>>>(Qall, Kt, Vt, sp, gateS, go);

  gemm_out<<<256, 256, 0, stream>>>(go, WtO, out);
}

// Round 15
// 154.371 us; speedup vs baseline: 1.1413x; 1.0167x over previous
//
#include <hip/hip_runtime.h>
#include <cstdint>
#include <cstddef>

typedef _Float16 f16;
typedef __attribute__((ext_vector_type(2))) __fp16 h16x2;   // builtin cvt_pkrtz/fdot2 type
typedef __attribute__((ext_vector_type(8))) _Float16 f16x8;
typedef __attribute__((ext_vector_type(4))) float f32x4;
typedef __attribute__((ext_vector_type(16))) float f32x16;
typedef const __attribute__((address_space(1))) uint32_t* gptr_t;
typedef __attribute__((address_space(3))) uint32_t* lptr_t;

#define DEV __device__ __forceinline__

DEV uint32_t pack2f16(float a, float b){
  union { f16 h[2]; uint32_t u; } p;
  p.h[0] = (f16)a; p.h[1] = (f16)b; return p.u;
}
DEV uint32_t cat2(f16 a, f16 b){
  union { f16 h[2]; uint32_t u; } p;
  p.h[0] = a; p.h[1] = b; return p.u;
}

// ---- problem constants
#define BB 2
#define SS 2048
#define HH 16
#define DD 64
#define NT (BB*SS)       // 4096 tokens
#define LLAT 256
#define LTOT 3328        // 2048 + 256 + 512 + 512
#define NTILE 26         // 3328 / 128 (128-key storage tiles)
#define LOG2E 1.44269504f
#define SC2 (0.125f*LOG2E)

// K' tile (per bh, per 128-key tile, 16KB): 16B chunk (key, dc) holds d=dc*8..+7,
//   at linear chunk pos key*8 + (dc ^ (key&7)).
// V' tile (16KB): 16B chunk (d, vc) holds PV k-slots s = vc*8+e; slot
//   s=16g+8hi+e -> key 32*(g>>1)+16*(g&1)+8*(e>>2)+4*hi+(e&3); chunk at
//   linear pos d*16 + (vc ^ (d&7)).
// Epilogue LDS transpose buffer Kl[128 keys][128 cols] f16, chunk-XOR'd:
#define KLIDX(key,col) (((key)<<7) + (((((col)>>3)^((key)&15)))<<3) + ((col)&7))

// ---------------------------------------------------------------- cvt f32->f16
__global__ void cvt_f32_f16(const float* __restrict__ src, f16* __restrict__ dst, size_t n){
  size_t i = ((size_t)blockIdx.x*blockDim.x + threadIdx.x)*4;
  if (i >= n) return;
  float4 v = *(const float4*)(src + i);
  uint2 o; o.x = pack2f16(v.x, v.y); o.y = pack2f16(v.z, v.w);
  *(uint2*)(dst + i) = o;
}

// ------------------------------- 5 weight transposes in one launch (z picks src)
__global__ void transpose_cvt5(const float* __restrict__ w0, const float* __restrict__ w1,
                               const float* __restrict__ w2, const float* __restrict__ w3,
                               const float* __restrict__ w4,
                               f16* __restrict__ dqkvg, f16* __restrict__ dout){
  __shared__ float t[32][33];
  int z = blockIdx.z;
  const float* src = z==0 ? w0 : z==1 ? w1 : z==2 ? w2 : z==3 ? w3 : w4;
  f16* dst = (z<4) ? (dqkvg + ((size_t)z<<20)) : dout;
  int tx = threadIdx.x, ty = threadIdx.y;
  int bx = blockIdx.x, by = blockIdx.y;
  #pragma unroll
  for (int i=0;i<4;i++){
    int r = ty + i*8;
    t[r][tx] = src[(size_t)(by*32 + r)*1024 + bx*32 + tx];
  }
  __syncthreads();
  #pragma unroll
  for (int i=0;i<4;i++){
    int r = ty + i*8;
    dst[(size_t)(bx*32 + r)*1024 + by*32 + tx] = (f16)t[tx][r];
  }
}

// GEMM staging (double-buffered, 64KB): row-major LDS rows of 128B, chunk pc
// within a row holds source k-chunk kc = pc ^ (row&7) (pre-swizzled source,
// linear GLDS dest). Coalesced: 8 lanes cover a full 128B row.
#define GSTAGE(Aptr, Bptr, Kd, ktv, bb) do { \
  char* Asb_ = smem + ((bb)<<14); \
  char* Bsb_ = smem + 32768 + ((bb)<<14); \
  _Pragma("unroll") \
  for (int u=0; u<4; ++u){ \
    int c = tid + u*256; \
    int row = c>>3, kc = (c&7) ^ (row&7); \
    __builtin_amdgcn_global_load_lds((gptr_t)((Aptr) + (m0+row)*(Kd) + (ktv) + kc*8), \
                                     (lptr_t)(Asb_ + c*16), 16, 0, 0); \
    __builtin_amdgcn_global_load_lds((gptr_t)((Bptr) + (n0+row)*(Kd) + (ktv) + kc*8), \
                                     (lptr_t)(Bsb_ + c*16), 16, 0, 0); \
  } \
} while(0)

// --------------------------------------------------------- fused QKVG GEMM
// [4096 x 4096] = x @ [wq|wk|wv|gw]. Double-buffered, 1 barrier/K-step.
// Epilogue fused per column region: q/k RMS+RoPE+pack, v -> V' tiles (sigma),
// gate -> sigmoid. All global writes coalesced 16B.
__launch_bounds__(256, 2)
__global__ void gemm_qkvg(const f16* __restrict__ A, const f16* __restrict__ Bt,
                          const float* __restrict__ qnw, const float* __restrict__ knw,
                          const float* __restrict__ fcos, const float* __restrict__ fsin,
                          const int* __restrict__ spp,
                          f16* __restrict__ Qall, char* __restrict__ Kt,
                          char* __restrict__ Vt, f16* __restrict__ gateS){
  __shared__ __align__(16) char smem[65536];
  const int tid = threadIdx.x;
  const int w = tid>>6, lane = tid&63;
  const int wr = w>>1, wc = w&1;
  const int l16 = lane&15, l4 = lane>>4;
  const int bid = blockIdx.x;
  const int x = bid&7, r_ = bid>>3;
  const int by = (x>>2)*16 + (r_>>3);
  const int bx = (x&3)*8 + (r_&7);
  const size_t m0 = (size_t)by*128, n0 = (size_t)bx*128;
  const int K = 1024;
  f32x4 acc[4][4];
  #pragma unroll
  for (int i=0;i<4;i++)
    #pragma unroll
    for (int j=0;j<4;j++) acc[i][j] = f32x4{0.f,0.f,0.f,0.f};

  GSTAGE(A, Bt, K, 0, 0);
  for (int t=0; t<16; ++t){
    __syncthreads();                       // drains STAGE(t)
    if (t < 15) GSTAGE(A, Bt, K, (t+1)*64, (t+1)&1);
    const char* Asb = smem + ((t&1)<<14);
    const char* Bsb = smem + 32768 + ((t&1)<<14);
    #pragma unroll
    for (int h2=0; h2<2; h2++){
      f16x8 af[4], bf[4];
      #pragma unroll
      for (int i=0;i<4;i++){
        int R = wr*64+i*16+l16;
        af[i] = *(const f16x8*)(Asb + R*128 + (((h2*4+l4)^(R&7))<<4));
      }
      #pragma unroll
      for (int j=0;j<4;j++){
        int R = wc*64+j*16+l16;
        bf[j] = *(const f16x8*)(Bsb + R*128 + (((h2*4+l4)^(R&7))<<4));
      }
      __builtin_amdgcn_s_setprio(1);
      #pragma unroll
      for (int i=0;i<4;i++)
        #pragma unroll
        for (int j=0;j<4;j++)
          acc[i][j] = __builtin_amdgcn_mfma_f32_16x16x32_f16(af[i], bf[j], acc[i][j], 0,0,0);
      __builtin_amdgcn_s_setprio(0);
    }
  }

  // ----------------------------- epilogue
  const int region = bx >> 3;           // 0 q, 1 k, 2 v, 3 gate
  const int s0 = (int)(m0 & 2047);
  const int b_ = (int)(m0 >> 11);
  const int tt = s0 >> 7;
  f16* Kl = (f16*)smem;                 // 32KB transpose buffer (reuse)
  __syncthreads();                      // all LDS tile reads done

  if (region <= 1){
    const int sp = *spp;
    const int h = (bx&7)*2 + wc;
    const float* wnorm = (region==0 ? qnw : knw) + h*64;
    const float wsc = (region==0) ? SC2 : 1.f;
    const bool do_rope = h < 8;
    #pragma unroll
    for (int i=0;i<4;i++){
      float s2[4];
      #pragma unroll
      for (int r=0;r<4;r++)
        s2[r] = acc[i][0][r]*acc[i][0][r] + acc[i][1][r]*acc[i][1][r]
              + acc[i][2][r]*acc[i][2][r] + acc[i][3][r]*acc[i][3][r];
      #pragma unroll
      for (int msk=1; msk<16; msk<<=1)
        #pragma unroll
        for (int r=0;r<4;r++) s2[r] += __shfl_xor(s2[r], msk, 64);
      float rsq[4];
      #pragma unroll
      for (int r=0;r<4;r++) rsq[r] = rsqrtf(s2[r]*(1.f/64.f) + 1e-5f) * wsc;
      #pragma unroll
      for (int j=0;j<4;j++){
        const int chd = j*16 + l16;
        const float wn = wnorm[chd];
        float v_[4];
        #pragma unroll
        for (int r=0;r<4;r++) v_[r] = acc[i][j][r]*rsq[r]*wn;
        if (do_rope){
          const float sgn = (l16&1) ? 1.f : -1.f;
          #pragma unroll
          for (int r=0;r<4;r++){
            int s_ = s0 + wr*64 + i*16 + l4*4 + r;
            float c_ = fcos[(size_t)(sp+s_)*32 + j*8 + (l16>>1)];
            float sn = fsin[(size_t)(sp+s_)*32 + j*8 + (l16>>1)];
            float pr = __shfl_xor(v_[r], 1, 64);
            v_[r] = v_[r]*c_ + sgn*pr*sn;
          }
        }
        #pragma unroll
        for (int r=0;r<4;r++){
          int key = wr*64 + i*16 + l4*4 + r;
          Kl[KLIDX(key, wc*64 + chd)] = (f16)v_[r];
        }
      }
    }
    __syncthreads();
    #pragma unroll
    for (int u=0;u<8;u++){
      int cc = tid + u*256;
      int h_loc = cc>>10, cl = cc&1023;
      int key = cl>>3, pc = cl&7;
      size_t bh2 = (size_t)(b_*16 + (bx&7)*2 + h_loc);
      if (region==0){
        f16x8 vv = *(const f16x8*)(Kl + KLIDX(key, h_loc*64 + pc*8));
        *(f16x8*)(Qall + (bh2*SS + s0 + key)*64 + pc*8) = vv;
      } else {
        int dc = pc ^ (key&7);
        f16x8 vv = *(const f16x8*)(Kl + KLIDX(key, h_loc*64 + dc*8));
        *(f16x8*)(Kt + (bh2*NTILE + tt)*16384 + (size_t)cl*16) = vv;
      }
    }
  } else if (region == 2){
    #pragma unroll
    for (int i=0;i<4;i++)
      #pragma unroll
      for (int j=0;j<4;j++)
        #pragma unroll
        for (int r=0;r<4;r++){
          int key = wr*64 + i*16 + l4*4 + r;
          Kl[KLIDX(key, wc*64 + j*16 + l16)] = (f16)acc[i][j][r];
        }
    __syncthreads();
    #pragma unroll
    for (int u=0;u<8;u++){
      int cc = tid + u*256;
      int h_loc = cc>>10, c = cc&1023;
      int d = c>>4, vc = (c&15)^(d&7);
      int g = vc>>1, hi2 = vc&1;
      int kb_ = 32*(g>>1) + 16*(g&1) + 4*hi2;
      int col = h_loc*64 + d;
      f16 a0 = Kl[KLIDX(kb_+0,col)],  a1 = Kl[KLIDX(kb_+1,col)];
      f16 a2 = Kl[KLIDX(kb_+2,col)],  a3 = Kl[KLIDX(kb_+3,col)];
      f16 a4 = Kl[KLIDX(kb_+8,col)],  a5 = Kl[KLIDX(kb_+9,col)];
      f16 a6 = Kl[KLIDX(kb_+10,col)], a7 = Kl[KLIDX(kb_+11,col)];
      uint4 o; o.x = cat2(a0,a1); o.y = cat2(a2,a3); o.z = cat2(a4,a5); o.w = cat2(a6,a7);
      size_t bh2 = (size_t)(b_*16 + (bx&7)*2 + h_loc);
      *(uint4*)(Vt + (bh2*NTILE + tt)*16384 + (size_t)c*16) = o;
    }
  } else {
    #pragma unroll
    for (int i=0;i<4;i++)
      #pragma unroll
      for (int j=0;j<4;j++)
        #pragma unroll
        for (int r=0;r<4;r++){
          int key = wr*64 + i*16 + l4*4 + r;
          float v_ = 1.f/(1.f + __builtin_amdgcn_exp2f(-acc[i][j][r]*LOG2E));
          Kl[KLIDX(key, wc*64 + j*16 + l16)] = (f16)v_;
        }
    __syncthreads();
    #pragma unroll
    for (int u=0;u<8;u++){
      int cc = tid + u*256;
      int key = cc>>4, ch = cc&15;
      f16x8 vv = *(const f16x8*)(Kl + KLIDX(key, ch*8));
      *(f16x8*)(gateS + (size_t)(m0 + key)*1024 + (bx&7)*128 + ch*8) = vv;
    }
  }
}

// ----------------------------------------------- final projection GEMM (f32 C)
// 64x128 tiles -> 512 blocks (was 256 = 1 block/CU, latency-starved).
// A dbuf 8KB each @0/@8K; B dbuf 16KB each @16K/@32K. 48KB LDS -> 3 blocks/CU.
__launch_bounds__(256, 3)
__global__ void gemm_out(const f16* __restrict__ A, const f16* __restrict__ Bt,
                         float* __restrict__ C){
  __shared__ __align__(16) char smem[49152];
  const int tid = threadIdx.x;
  const int w = tid>>6, lane = tid&63;
  const int wr = w>>1, wc = w&1;
  const int l16 = lane&15, l4 = lane>>4;
  const int bid = blockIdx.x;
  const int by = (bid&7)*8 + ((bid>>3)>>3);   // 64 m-tiles, XCD-chunked
  const int bx = (bid>>3)&7;
  const size_t m0 = (size_t)by*64, n0 = (size_t)bx*128;
  const int K = 1024;
  f32x4 acc[2][4];
  #pragma unroll
  for (int i=0;i<2;i++)
    #pragma unroll
    for (int j=0;j<4;j++) acc[i][j] = f32x4{0.f,0.f,0.f,0.f};

  #define GSTAGE_O(ktv, bb) do { \
    char* Asb_ = smem + ((bb)<<13); \
    char* Bsb_ = smem + 16384 + ((bb)<<14); \
    _Pragma("unroll") \
    for (int u=0; u<2; ++u){ \
      int c = tid + u*256; \
      int row = c>>3, kc = (c&7) ^ (row&7); \
      __builtin_amdgcn_global_load_lds((gptr_t)(A + (m0+row)*K + (ktv) + kc*8), \
                                       (lptr_t)(Asb_ + c*16), 16, 0, 0); \
    } \
    _Pragma("unroll") \
    for (int u=0; u<4; ++u){ \
      int c = tid + u*256; \
      int row = c>>3, kc = (c&7) ^ (row&7); \
      __builtin_amdgcn_global_load_lds((gptr_t)(Bt + (n0+row)*K + (ktv) + kc*8), \
                                       (lptr_t)(Bsb_ + c*16), 16, 0, 0); \
    } \
  } while(0)

  GSTAGE_O(0, 0);
  for (int t=0; t<16; ++t){
    __syncthreads();
    if (t < 15) GSTAGE_O((t+1)*64, (t+1)&1);
    const char* Asb = smem + ((t&1)<<13);
    const char* Bsb = smem + 16384 + ((t&1)<<14);
    #pragma unroll
    for (int h2=0; h2<2; h2++){
      f16x8 af[2], bf[4];
      #pragma unroll
      for (int i=0;i<2;i++){
        int R = wr*32+i*16+l16;
        af[i] = *(const f16x8*)(Asb + R*128 + (((h2*4+l4)^(R&7))<<4));
      }
      #pragma unroll
      for (int j=0;j<4;j++){
        int R = wc*64+j*16+l16;
        bf[j] = *(const f16x8*)(Bsb + R*128 + (((h2*4+l4)^(R&7))<<4));
      }
      __builtin_amdgcn_s_setprio(1);
      #pragma unroll
      for (int i=0;i<2;i++)
        #pragma unroll
        for (int j=0;j<4;j++)
          acc[i][j] = __builtin_amdgcn_mfma_f32_16x16x32_f16(af[i], bf[j], acc[i][j], 0,0,0);
      __builtin_amdgcn_s_setprio(0);
    }
  }
  #undef GSTAGE_O
  #pragma unroll
  for (int i=0;i<2;i++)
    #pragma unroll
    for (int j=0;j<4;j++)
      #pragma unroll
      for (int r=0;r<4;r++)
        C[(m0 + wr*32 + i*16 + l4*4 + r)*1024 + n0 + wc*64 + j*16 + l16] = acc[i][j][r];
}

// -------------------------------------------- pack ALL context K -> K' tiles
__launch_bounds__(256)
__global__ void pack_k_all(const float* __restrict__ lat, const float* __restrict__ txt,
                           const float* __restrict__ spk, char* __restrict__ Kt){
  int unit = blockIdx.x*16 + (threadIdx.x>>4);
  int ll = threadIdx.x & 15;
  int l = unit % 1280; int bh = unit / 1280;
  int b = bh >> 4, h = bh & 15;
  const float* src; int nL, li, l0;
  if (l < 256)      { src = lat; nL = 256; li = l;     l0 = 2048; }
  else if (l < 768) { src = txt; nL = 512; li = l-256; l0 = 2304; }
  else              { src = spk; nL = 512; li = l-768; l0 = 2816; }
  float4 v = *(const float4*)(src + (((size_t)b*nL + li)*16 + h)*64 + ll*4);
  uint2 o; o.x = pack2f16(v.x, v.y); o.y = pack2f16(v.z, v.w);
  int s = l0 + li; int tt = s >> 7, kl = s & 127;
  *(uint2*)(Kt + ((size_t)bh*NTILE + tt)*16384
               + (kl*8 + ((ll>>1) ^ (kl&7)))*16 + (ll&1)*8) = o;
}

// --------------------------- pack ALL context V -> V' tiles (sigma + bank XOR)
__launch_bounds__(256)
__global__ void pack_v_all(const float* __restrict__ lat, const float* __restrict__ txt,
                           const float* __restrict__ spk, char* __restrict__ Vt){
  __shared__ float t[128*68];
  const int bh = blockIdx.y, b = bh>>4, h = bh&15;
  const int tz = blockIdx.x;              // 0..9 -> storage tile 16+tz
  const float* src; int tl, nB;
  if (tz < 2)      { src = lat; tl = tz;   nB = 256; }
  else if (tz < 6) { src = txt; tl = tz-2; nB = 512; }
  else             { src = spk; tl = tz-6; nB = 512; }
  const float* sb = src + ((size_t)b*nB + tl*128)*1024 + h*64;
  const int tid = threadIdx.x;
  {
    int row = tid >> 1, half = tid & 1;
    #pragma unroll
    for (int i=0;i<8;i++){
      float4 v = *(const float4*)(sb + (size_t)row*1024 + half*32 + i*4);
      *(float4*)(&t[row*68 + half*32 + i*4]) = v;
    }
  }
  __syncthreads();
  char* dstb = Vt + ((size_t)bh*NTILE + 16 + tz)*16384;
  #pragma unroll
  for (int u=0;u<4;u++){
    int c = tid + u*256;
    int d = c >> 4;
    int vc = (c & 15) ^ (d & 7);
    int g = vc >> 1, hi = vc & 1;
    int kb_ = 32*(g>>1) + 16*(g&1) + 4*hi;
    uint4 o;
    o.x = pack2f16(t[(kb_+0)*68+d],  t[(kb_+1)*68+d]);
    o.y = pack2f16(t[(kb_+2)*68+d],  t[(kb_+3)*68+d]);
    o.z = pack2f16(t[(kb_+8)*68+d],  t[(kb_+9)*68+d]);
    o.w = pack2f16(t[(kb_+10)*68+d], t[(kb_+11)*68+d]);
    *(uint4*)(dstb + c*16) = o;
  }
}

// -------------------------------------------------------------- flash attention
// NON-SPLIT, 128-key staging tiles (26 iterations, 1 barrier each; 64KB LDS,
// grid 512 = 2 blocks/CU either way, so larger tiles are occupancy-free).
// Fixed-max softmax (p = 2^s exact-bounded), pkrtz + fdot2 dual-lsum,
// fully-masked latent 128-tiles skipped, gate fused into the f16 epilogue.
__launch_bounds__(256, 2)
__global__ void attn_fwd(const f16* __restrict__ Qall, const char* __restrict__ Kt,
                         const char* __restrict__ Vt, const int* __restrict__ spp,
                         const f16* __restrict__ gateS, f16* __restrict__ go){
  __shared__ __align__(16) char Ks[2][16384];
  __shared__ __align__(16) char Vs[2][16384];
  const int sp = *spp;
  const int tid = threadIdx.x, lane = tid & 63, w = tid >> 6;
  const int l31 = lane & 31, hi = lane >> 5, l7 = lane & 7;
  const int bid = blockIdx.x;
  const int bh = (bid&7)*4 + ((bid>>3)>>4);   // 64 blocks per XCD share 4 bh
  const int qb = (bid>>3) & 15;
  const int b = bh >> 4, h = bh & 15;
  const int q0w = qb*128 + w*32;
  const f16*  Qb = Qall + (size_t)bh*SS*DD;
  const char* Kb = Kt + (size_t)bh*NTILE*16384;
  const char* Vb = Vt + (size_t)bh*NTILE*16384;

  // 128-key tiles 0..25; latent = 16,17. Skip fully-masked ones.
  const int vl   = min(256, (sp + 3) >> 2);   // valid latent keys
  const int Ms   = 16 + ((vl + 127) >> 7);    // first fully-masked tile (16..18)
  const int skip = 18 - Ms;                   // 0..2 tiles skipped
  const int nt   = 26 - skip;
  #define TMAP(ti) ((ti) < Ms ? (ti) : (ti) + skip)

  f16x8 qf[4];
  {
    const f16* qrow = Qb + (size_t)(q0w + l31)*DD + hi*8;
    #pragma unroll
    for (int ks=0; ks<4; ks++) qf[ks] = *(const f16x8*)(qrow + ks*16);
  }

  f32x16 oA = {0,0,0,0,0,0,0,0,0,0,0,0,0,0,0,0};
  f32x16 oB = {0,0,0,0,0,0,0,0,0,0,0,0,0,0,0,0};
  float lsum0 = 0.f, lsum1 = 0.f;
  const h16x2 ones2 = {(__fp16)1.f, (__fp16)1.f};

  // stage full 16KB K' + V' tiles, linear copy
  #define STAGE(bi, T) do { \
    const char* kb_ = Kb + (size_t)(T)*16384; \
    const char* vb_ = Vb + (size_t)(T)*16384; \
    _Pragma("unroll") \
    for (int u=0; u<4; ++u){ \
      int c = tid + u*256; \
      __builtin_amdgcn_global_load_lds((gptr_t)(kb_ + c*16), (lptr_t)(&Ks[bi][c*16]), 16, 0, 0); \
      __builtin_amdgcn_global_load_lds((gptr_t)(vb_ + c*16), (lptr_t)(&Vs[bi][c*16]), 16, 0, 0); \
    } \
  } while(0)

  STAGE(0, TMAP(0));
  for (int ti = 0; ti < nt; ++ti){
    __syncthreads();
    if (ti < nt-1) STAGE((ti+1)&1, TMAP(ti+1));
    const char* Ksb = Ks[ti&1];
    const char* Vsb = Vs[ti&1];
    const int T = TMAP(ti);
    const bool maskt = (unsigned)(T-16) < 2u;   // latent 128-key tiles 16,17
    const int ktl = (T-16)*128;
    #pragma unroll
    for (int kb=0; kb<4; ++kb){
      f16x8 kf[4];
      #pragma unroll
      for (int ks=0; ks<4; ks++)
        kf[ks] = *(const f16x8*)(Ksb + (32*kb + l31)*128 + (((2*ks+hi) ^ l7))*16);
      f32x16 acc = {0,0,0,0,0,0,0,0,0,0,0,0,0,0,0,0};
      __builtin_amdgcn_s_setprio(1);
      #pragma unroll
      for (int ks=0; ks<4; ks++)
        acc = __builtin_amdgcn_mfma_f32_32x32x16_f16(kf[ks], qf[ks], acc, 0,0,0);
      __builtin_amdgcn_s_setprio(0);
      if (maskt){
        #pragma unroll
        for (int r=0;r<16;r++){
          int kk = ktl + kb*32 + (r&3) + 8*(r>>2) + 4*hi;
          if (kk*4 >= sp) acc[r] = -1e5f;
        }
      }
      // fixed-max softmax: p = 2^s (bounded by 2^11.54 < f16 max).
      // pkrtz packs the pair in 1 instr; fdot2 with ones accumulates lsum
      // from the SAME rounded f16 values that feed PV. Two lsum chains (ILP).
      uint32_t pk[8];
      #pragma unroll
      for (int i=0;i<8;i++){
        float p0 = __builtin_amdgcn_exp2f(acc[2*i]);
        float p1 = __builtin_amdgcn_exp2f(acc[2*i+1]);
        h16x2 h2 = __builtin_amdgcn_cvt_pkrtz(p0, p1);
#if __has_builtin(__builtin_amdgcn_fdot2)
        if (i & 1) lsum1 = __builtin_amdgcn_fdot2(h2, ones2, lsum1, false);
        else       lsum0 = __builtin_amdgcn_fdot2(h2, ones2, lsum0, false);
#else
        if (i & 1) lsum1 += (float)h2[0] + (float)h2[1];
        else       lsum0 += (float)h2[0] + (float)h2[1];
#endif
        union { h16x2 v; uint32_t u; } cv; cv.v = h2; pk[i] = cv.u;
      }
      __builtin_amdgcn_s_setprio(1);
      #pragma unroll
      for (int gg=0; gg<2; gg++){
        union { uint4 u; f16x8 v; } pa;
        pa.u = make_uint4(pk[4*gg], pk[4*gg+1], pk[4*gg+2], pk[4*gg+3]);
        int cofs = ((2*(2*kb+gg) + hi) ^ l7)*16;
        f16x8 v0 = *(const f16x8*)(Vsb + l31*256 + cofs);
        f16x8 v1 = *(const f16x8*)(Vsb + (32+l31)*256 + cofs);
        oA = __builtin_amdgcn_mfma_f32_32x32x16_f16(pa.v, v0, oA, 0,0,0);
        oB = __builtin_amdgcn_mfma_f32_32x32x16_f16(pa.v, v1, oB, 0,0,0);
      }
      __builtin_amdgcn_s_setprio(0);
    }
  }
  #undef STAGE
  #undef TMAP

  float lsum = lsum0 + lsum1;
  lsum += __shfl_xor(lsum, 32, 64);
  float linv = 1.f / lsum;
  #pragma unroll
  for (int r=0;r<16;r++){
    int qo = (r&3) + 8*(r>>2) + 4*hi;
    float nv = __shfl(linv, qo, 64);
    size_t token = (size_t)(b*SS + q0w + qo);
    const f16* gr = gateS + token*1024 + h*64;
    float s0_ = (float)gr[l31], s1_ = (float)gr[32 + l31];
    f16* orow = go + token*1024 + h*64;
    orow[l31]      = (f16)(oA[r]*nv*s0_);
    orow[32 + l31] = (f16)(oB[r]*nv*s1_);
  }
}

// ---------------------------------------------------------------------- launch
extern "C" void kernel_launch(void* const* d_in, const int* in_sizes, int n_in,
                              void* d_out, int out_size, void* d_ws, size_t ws_size,
                              hipStream_t stream){
  const float* x        = (const float*)d_in[0];
  const float* fcos     = (const float*)d_in[3];
  const float* fsin     = (const float*)d_in[4];
  const float* kv_txt_k = (const float*)d_in[5];
  const float* kv_txt_v = (const float*)d_in[6];
  const float* kv_spk_k = (const float*)d_in[7];
  const float* kv_spk_v = (const float*)d_in[8];
  const float* kv_lat_k = (const float*)d_in[9];
  const float* kv_lat_v = (const float*)d_in[10];
  const int*   sp       = (const int*)d_in[11];
  const float* wq       = (const float*)d_in[12];
  const float* wk       = (const float*)d_in[13];
  const float* wv       = (const float*)d_in[14];
  const float* gw       = (const float*)d_in[15];
  const float* wo       = (const float*)d_in[16];
  const float* qnw      = (const float*)d_in[17];
  const float* knw      = (const float*)d_in[18];
  float* out = (float*)d_out;
  char* ws = (char*)d_ws;

  f16*   xh     = (f16*)  (ws + 0);          // 8 MB
  f16*   WtQKVG = (f16*)  (ws + 8388608);    // 8 MB
  f16*   WtO    = (f16*)  (ws + 16777216);   // 2 MB
  f16*   gateS  = (f16*)  (ws + 18874368);   // 8 MB  f16 sigma(gate)
  f16*   Qall   = (f16*)  (ws + 27262976);   // 8 MB  (B,H,S,D)
  char*  Kt     = (char*) (ws + 35651584);   // 13.6 MB K' tiles
  char*  Vt     = (char*) (ws + 49283072);   // 13.6 MB V' tiles
  f16*   go     = (f16*)  (ws + 62914560);   // 8 MB

  cvt_f32_f16<<<4096, 256, 0, stream>>>(x, xh, (size_t)NT*1024);
  dim3 tb(32,8);
  transpose_cvt5<<<dim3(32,32,5), tb, 0, stream>>>(wq, wk, wv, gw, wo, WtQKVG, WtO);

  gemm_qkvg<<<1024, 256, 0, stream>>>(xh, WtQKVG, qnw, knw, fcos, fsin, sp,
                                      Qall, Kt, Vt, gateS);

  pack_k_all<<<2560, 256, 0, stream>>>(kv_lat_k, kv_txt_k, kv_spk_k, Kt);
  pack_v_all<<<dim3(10,32), 256, 0, stream>>>(kv_lat_v, kv_txt_v, kv_spk_v, Vt);

  attn_fwd<<<512, 256, 0, stream>>>(Qall, Kt, Vt, sp, gateS, go);

  gemm_out<<<512, 256, 0, stream>>>(go, WtO, out);
}

// Round 16
// 151.472 us; speedup vs baseline: 1.1632x; 1.0191x over previous
//
#include <hip/hip_runtime.h>
#include <cstdint>
#include <cstddef>

typedef _Float16 f16;
typedef __attribute__((ext_vector_type(2))) __fp16 h16x2;   // builtin cvt_pkrtz/fdot2 type
typedef __attribute__((ext_vector_type(8))) _Float16 f16x8;
typedef __attribute__((ext_vector_type(4))) float f32x4;
typedef __attribute__((ext_vector_type(16))) float f32x16;
typedef const __attribute__((address_space(1))) uint32_t* gptr_t;
typedef __attribute__((address_space(3))) uint32_t* lptr_t;

#define DEV __device__ __forceinline__

DEV uint32_t pack2f16(float a, float b){
  union { f16 h[2]; uint32_t u; } p;
  p.h[0] = (f16)a; p.h[1] = (f16)b; return p.u;
}
DEV uint32_t cat2(f16 a, f16 b){
  union { f16 h[2]; uint32_t u; } p;
  p.h[0] = a; p.h[1] = b; return p.u;
}

// ---- problem constants
#define BB 2
#define SS 2048
#define HH 16
#define DD 64
#define NT (BB*SS)       // 4096 tokens
#define LLAT 256
#define LTOT 3328        // 2048 + 256 + 512 + 512
#define NTILE 26         // 3328 / 128 (128-key storage tiles)
#define LOG2E 1.44269504f
#define SC2 (0.125f*LOG2E)

// K' tile (per bh, per 128-key tile, 16KB): 16B chunk (key, dc) holds d=dc*8..+7,
//   at linear chunk pos key*8 + (dc ^ (key&7)).
// V' tile (16KB): 16B chunk (d, vc) holds PV k-slots s = vc*8+e; slot
//   s=16g+8hi+e -> key 32*(g>>1)+16*(g&1)+8*(e>>2)+4*hi+(e&3); chunk at
//   linear pos d*16 + (vc ^ (d&7)).
// Epilogue LDS transpose buffer Kl[128 keys][128 cols] f16, chunk-XOR'd:
#define KLIDX(key,col) (((key)<<7) + (((((col)>>3)^((key)&15)))<<3) + ((col)&7))

// ---------------- fused prep: x f32->f16 (blocks 0..4095) + 5 weight
// ---------------- transposes (blocks 4096..9215; 1024 blocks each)
__global__ void prep_all(const float* __restrict__ x, f16* __restrict__ xh,
                         const float* __restrict__ w0, const float* __restrict__ w1,
                         const float* __restrict__ w2, const float* __restrict__ w3,
                         const float* __restrict__ w4,
                         f16* __restrict__ dqkvg, f16* __restrict__ dout){
  __shared__ float t[32][33];
  const int bid = blockIdx.x;
  if (bid < 4096){
    size_t i = ((size_t)bid*256 + threadIdx.x)*4;
    float4 v = *(const float4*)(x + i);
    uint2 o; o.x = pack2f16(v.x, v.y); o.y = pack2f16(v.z, v.w);
    *(uint2*)(xh + i) = o;
  } else {
    int id = bid - 4096;
    int z = id >> 10, rem = id & 1023;
    int bx = rem & 31, by = rem >> 5;
    const float* src = z==0 ? w0 : z==1 ? w1 : z==2 ? w2 : z==3 ? w3 : w4;
    f16* dst = (z<4) ? (dqkvg + ((size_t)z<<20)) : dout;
    int tx = threadIdx.x & 31, ty = threadIdx.x >> 5;
    #pragma unroll
    for (int i=0;i<4;i++){
      int r = ty + i*8;
      t[r][tx] = src[(size_t)(by*32 + r)*1024 + bx*32 + tx];
    }
    __syncthreads();
    #pragma unroll
    for (int i=0;i<4;i++){
      int r = ty + i*8;
      dst[(size_t)(bx*32 + r)*1024 + by*32 + tx] = (f16)t[tx][r];
    }
  }
}

// GEMM staging (double-buffered, 64KB): row-major LDS rows of 128B, chunk pc
// within a row holds source k-chunk kc = pc ^ (row&7) (pre-swizzled source,
// linear GLDS dest). Coalesced: 8 lanes cover a full 128B row.
#define GSTAGE(Aptr, Bptr, Kd, ktv, bb) do { \
  char* Asb_ = smem + ((bb)<<14); \
  char* Bsb_ = smem + 32768 + ((bb)<<14); \
  _Pragma("unroll") \
  for (int u=0; u<4; ++u){ \
    int c = tid + u*256; \
    int row = c>>3, kc = (c&7) ^ (row&7); \
    __builtin_amdgcn_global_load_lds((gptr_t)((Aptr) + (m0+row)*(Kd) + (ktv) + kc*8), \
                                     (lptr_t)(Asb_ + c*16), 16, 0, 0); \
    __builtin_amdgcn_global_load_lds((gptr_t)((Bptr) + (n0+row)*(Kd) + (ktv) + kc*8), \
                                     (lptr_t)(Bsb_ + c*16), 16, 0, 0); \
  } \
} while(0)

// --------------------------------------------------------- fused QKVG GEMM
// [4096 x 4096] = x @ [wq|wk|wv|gw]. Double-buffered, 1 barrier/K-step.
// Epilogue fused per column region: q/k RMS+RoPE+pack, v -> V' tiles (sigma),
// gate -> sigmoid. All global writes coalesced 16B.
__launch_bounds__(256, 2)
__global__ void gemm_qkvg(const f16* __restrict__ A, const f16* __restrict__ Bt,
                          const float* __restrict__ qnw, const float* __restrict__ knw,
                          const float* __restrict__ fcos, const float* __restrict__ fsin,
                          const int* __restrict__ spp,
                          f16* __restrict__ Qall, char* __restrict__ Kt,
                          char* __restrict__ Vt, f16* __restrict__ gateS){
  __shared__ __align__(16) char smem[65536];
  const int tid = threadIdx.x;
  const int w = tid>>6, lane = tid&63;
  const int wr = w>>1, wc = w&1;
  const int l16 = lane&15, l4 = lane>>4;
  const int bid = blockIdx.x;
  const int x = bid&7, r_ = bid>>3;
  const int by = (x>>2)*16 + (r_>>3);
  const int bx = (x&3)*8 + (r_&7);
  const size_t m0 = (size_t)by*128, n0 = (size_t)bx*128;
  const int K = 1024;
  f32x4 acc[4][4];
  #pragma unroll
  for (int i=0;i<4;i++)
    #pragma unroll
    for (int j=0;j<4;j++) acc[i][j] = f32x4{0.f,0.f,0.f,0.f};

  GSTAGE(A, Bt, K, 0, 0);
  for (int t=0; t<16; ++t){
    __syncthreads();                       // drains STAGE(t)
    if (t < 15) GSTAGE(A, Bt, K, (t+1)*64, (t+1)&1);
    const char* Asb = smem + ((t&1)<<14);
    const char* Bsb = smem + 32768 + ((t&1)<<14);
    #pragma unroll
    for (int h2=0; h2<2; h2++){
      f16x8 af[4], bf[4];
      #pragma unroll
      for (int i=0;i<4;i++){
        int R = wr*64+i*16+l16;
        af[i] = *(const f16x8*)(Asb + R*128 + (((h2*4+l4)^(R&7))<<4));
      }
      #pragma unroll
      for (int j=0;j<4;j++){
        int R = wc*64+j*16+l16;
        bf[j] = *(const f16x8*)(Bsb + R*128 + (((h2*4+l4)^(R&7))<<4));
      }
      __builtin_amdgcn_s_setprio(1);
      #pragma unroll
      for (int i=0;i<4;i++)
        #pragma unroll
        for (int j=0;j<4;j++)
          acc[i][j] = __builtin_amdgcn_mfma_f32_16x16x32_f16(af[i], bf[j], acc[i][j], 0,0,0);
      __builtin_amdgcn_s_setprio(0);
    }
  }

  // ----------------------------- epilogue
  const int region = bx >> 3;           // 0 q, 1 k, 2 v, 3 gate
  const int s0 = (int)(m0 & 2047);
  const int b_ = (int)(m0 >> 11);
  const int tt = s0 >> 7;
  f16* Kl = (f16*)smem;                 // 32KB transpose buffer (reuse)
  __syncthreads();                      // all LDS tile reads done

  if (region <= 1){
    const int sp = *spp;
    const int h = (bx&7)*2 + wc;
    const float* wnorm = (region==0 ? qnw : knw) + h*64;
    const float wsc = (region==0) ? SC2 : 1.f;
    const bool do_rope = h < 8;
    #pragma unroll
    for (int i=0;i<4;i++){
      float s2[4];
      #pragma unroll
      for (int r=0;r<4;r++)
        s2[r] = acc[i][0][r]*acc[i][0][r] + acc[i][1][r]*acc[i][1][r]
              + acc[i][2][r]*acc[i][2][r] + acc[i][3][r]*acc[i][3][r];
      #pragma unroll
      for (int msk=1; msk<16; msk<<=1)
        #pragma unroll
        for (int r=0;r<4;r++) s2[r] += __shfl_xor(s2[r], msk, 64);
      float rsq[4];
      #pragma unroll
      for (int r=0;r<4;r++) rsq[r] = rsqrtf(s2[r]*(1.f/64.f) + 1e-5f) * wsc;
      #pragma unroll
      for (int j=0;j<4;j++){
        const int chd = j*16 + l16;
        const float wn = wnorm[chd];
        float v_[4];
        #pragma unroll
        for (int r=0;r<4;r++) v_[r] = acc[i][j][r]*rsq[r]*wn;
        if (do_rope){
          const float sgn = (l16&1) ? 1.f : -1.f;
          #pragma unroll
          for (int r=0;r<4;r++){
            int s_ = s0 + wr*64 + i*16 + l4*4 + r;
            float c_ = fcos[(size_t)(sp+s_)*32 + j*8 + (l16>>1)];
            float sn = fsin[(size_t)(sp+s_)*32 + j*8 + (l16>>1)];
            float pr = __shfl_xor(v_[r], 1, 64);
            v_[r] = v_[r]*c_ + sgn*pr*sn;
          }
        }
        #pragma unroll
        for (int r=0;r<4;r++){
          int key = wr*64 + i*16 + l4*4 + r;
          Kl[KLIDX(key, wc*64 + chd)] = (f16)v_[r];
        }
      }
    }
    __syncthreads();
    #pragma unroll
    for (int u=0;u<8;u++){
      int cc = tid + u*256;
      int h_loc = cc>>10, cl = cc&1023;
      int key = cl>>3, pc = cl&7;
      size_t bh2 = (size_t)(b_*16 + (bx&7)*2 + h_loc);
      if (region==0){
        f16x8 vv = *(const f16x8*)(Kl + KLIDX(key, h_loc*64 + pc*8));
        *(f16x8*)(Qall + (bh2*SS + s0 + key)*64 + pc*8) = vv;
      } else {
        int dc = pc ^ (key&7);
        f16x8 vv = *(const f16x8*)(Kl + KLIDX(key, h_loc*64 + dc*8));
        *(f16x8*)(Kt + (bh2*NTILE + tt)*16384 + (size_t)cl*16) = vv;
      }
    }
  } else if (region == 2){
    #pragma unroll
    for (int i=0;i<4;i++)
      #pragma unroll
      for (int j=0;j<4;j++)
        #pragma unroll
        for (int r=0;r<4;r++){
          int key = wr*64 + i*16 + l4*4 + r;
          Kl[KLIDX(key, wc*64 + j*16 + l16)] = (f16)acc[i][j][r];
        }
    __syncthreads();
    #pragma unroll
    for (int u=0;u<8;u++){
      int cc = tid + u*256;
      int h_loc = cc>>10, c = cc&1023;
      int d = c>>4, vc = (c&15)^(d&7);
      int g = vc>>1, hi2 = vc&1;
      int kb_ = 32*(g>>1) + 16*(g&1) + 4*hi2;
      int col = h_loc*64 + d;
      f16 a0 = Kl[KLIDX(kb_+0,col)],  a1 = Kl[KLIDX(kb_+1,col)];
      f16 a2 = Kl[KLIDX(kb_+2,col)],  a3 = Kl[KLIDX(kb_+3,col)];
      f16 a4 = Kl[KLIDX(kb_+8,col)],  a5 = Kl[KLIDX(kb_+9,col)];
      f16 a6 = Kl[KLIDX(kb_+10,col)], a7 = Kl[KLIDX(kb_+11,col)];
      uint4 o; o.x = cat2(a0,a1); o.y = cat2(a2,a3); o.z = cat2(a4,a5); o.w = cat2(a6,a7);
      size_t bh2 = (size_t)(b_*16 + (bx&7)*2 + h_loc);
      *(uint4*)(Vt + (bh2*NTILE + tt)*16384 + (size_t)c*16) = o;
    }
  } else {
    #pragma unroll
    for (int i=0;i<4;i++)
      #pragma unroll
      for (int j=0;j<4;j++)
        #pragma unroll
        for (int r=0;r<4;r++){
          int key = wr*64 + i*16 + l4*4 + r;
          float v_ = 1.f/(1.f + __builtin_amdgcn_exp2f(-acc[i][j][r]*LOG2E));
          Kl[KLIDX(key, wc*64 + j*16 + l16)] = (f16)v_;
        }
    __syncthreads();
    #pragma unroll
    for (int u=0;u<8;u++){
      int cc = tid + u*256;
      int key = cc>>4, ch = cc&15;
      f16x8 vv = *(const f16x8*)(Kl + KLIDX(key, ch*8));
      *(f16x8*)(gateS + (size_t)(m0 + key)*1024 + (bx&7)*128 + ch*8) = vv;
    }
  }
}

// ----------------------------------------------- final projection GEMM (f32 C)
// 64x128 tiles -> 512 blocks. A dbuf 8KB each @0/@8K; B dbuf 16KB @16K/@32K.
__launch_bounds__(256, 3)
__global__ void gemm_out(const f16* __restrict__ A, const f16* __restrict__ Bt,
                         float* __restrict__ C){
  __shared__ __align__(16) char smem[49152];
  const int tid = threadIdx.x;
  const int w = tid>>6, lane = tid&63;
  const int wr = w>>1, wc = w&1;
  const int l16 = lane&15, l4 = lane>>4;
  const int bid = blockIdx.x;
  const int by = (bid&7)*8 + ((bid>>3)>>3);   // 64 m-tiles, XCD-chunked
  const int bx = (bid>>3)&7;
  const size_t m0 = (size_t)by*64, n0 = (size_t)bx*128;
  const int K = 1024;
  f32x4 acc[2][4];
  #pragma unroll
  for (int i=0;i<2;i++)
    #pragma unroll
    for (int j=0;j<4;j++) acc[i][j] = f32x4{0.f,0.f,0.f,0.f};

  #define GSTAGE_O(ktv, bb) do { \
    char* Asb_ = smem + ((bb)<<13); \
    char* Bsb_ = smem + 16384 + ((bb)<<14); \
    _Pragma("unroll") \
    for (int u=0; u<2; ++u){ \
      int c = tid + u*256; \
      int row = c>>3, kc = (c&7) ^ (row&7); \
      __builtin_amdgcn_global_load_lds((gptr_t)(A + (m0+row)*K + (ktv) + kc*8), \
                                       (lptr_t)(Asb_ + c*16), 16, 0, 0); \
    } \
    _Pragma("unroll") \
    for (int u=0; u<4; ++u){ \
      int c = tid + u*256; \
      int row = c>>3, kc = (c&7) ^ (row&7); \
      __builtin_amdgcn_global_load_lds((gptr_t)(Bt + (n0+row)*K + (ktv) + kc*8), \
                                       (lptr_t)(Bsb_ + c*16), 16, 0, 0); \
    } \
  } while(0)

  GSTAGE_O(0, 0);
  for (int t=0; t<16; ++t){
    __syncthreads();
    if (t < 15) GSTAGE_O((t+1)*64, (t+1)&1);
    const char* Asb = smem + ((t&1)<<13);
    const char* Bsb = smem + 16384 + ((t&1)<<14);
    #pragma unroll
    for (int h2=0; h2<2; h2++){
      f16x8 af[2], bf[4];
      #pragma unroll
      for (int i=0;i<2;i++){
        int R = wr*32+i*16+l16;
        af[i] = *(const f16x8*)(Asb + R*128 + (((h2*4+l4)^(R&7))<<4));
      }
      #pragma unroll
      for (int j=0;j<4;j++){
        int R = wc*64+j*16+l16;
        bf[j] = *(const f16x8*)(Bsb + R*128 + (((h2*4+l4)^(R&7))<<4));
      }
      __builtin_amdgcn_s_setprio(1);
      #pragma unroll
      for (int i=0;i<2;i++)
        #pragma unroll
        for (int j=0;j<4;j++)
          acc[i][j] = __builtin_amdgcn_mfma_f32_16x16x32_f16(af[i], bf[j], acc[i][j], 0,0,0);
      __builtin_amdgcn_s_setprio(0);
    }
  }
  #undef GSTAGE_O
  #pragma unroll
  for (int i=0;i<2;i++)
    #pragma unroll
    for (int j=0;j<4;j++)
      #pragma unroll
      for (int r=0;r<4;r++)
        C[(m0 + wr*32 + i*16 + l4*4 + r)*1024 + n0 + wc*64 + j*16 + l16] = acc[i][j][r];
}

// ------------- fused context pack: K (blocks 0..2559) + V (blocks 2560..2879)
__launch_bounds__(256)
__global__ void pack_all(const float* __restrict__ lat_k, const float* __restrict__ txt_k,
                         const float* __restrict__ spk_k,
                         const float* __restrict__ lat_v, const float* __restrict__ txt_v,
                         const float* __restrict__ spk_v,
                         char* __restrict__ Kt, char* __restrict__ Vt){
  __shared__ float t[128*68];
  const int bid = blockIdx.x;
  const int tid = threadIdx.x;
  if (bid < 2560){
    int unit = bid*16 + (tid>>4);
    int ll = tid & 15;
    int l = unit % 1280; int bh = unit / 1280;
    int b = bh >> 4, h = bh & 15;
    const float* src; int nL, li, l0;
    if (l < 256)      { src = lat_k; nL = 256; li = l;     l0 = 2048; }
    else if (l < 768) { src = txt_k; nL = 512; li = l-256; l0 = 2304; }
    else              { src = spk_k; nL = 512; li = l-768; l0 = 2816; }
    float4 v = *(const float4*)(src + (((size_t)b*nL + li)*16 + h)*64 + ll*4);
    uint2 o; o.x = pack2f16(v.x, v.y); o.y = pack2f16(v.z, v.w);
    int s = l0 + li; int tt = s >> 7, kl = s & 127;
    *(uint2*)(Kt + ((size_t)bh*NTILE + tt)*16384
                 + (kl*8 + ((ll>>1) ^ (kl&7)))*16 + (ll&1)*8) = o;
  } else {
    int id = bid - 2560;
    int tz = id % 10, bh = id / 10;
    int b = bh>>4, h = bh&15;
    const float* src; int tl, nB;
    if (tz < 2)      { src = lat_v; tl = tz;   nB = 256; }
    else if (tz < 6) { src = txt_v; tl = tz-2; nB = 512; }
    else             { src = spk_v; tl = tz-6; nB = 512; }
    const float* sb = src + ((size_t)b*nB + tl*128)*1024 + h*64;
    {
      int row = tid >> 1, half = tid & 1;
      #pragma unroll
      for (int i=0;i<8;i++){
        float4 v = *(const float4*)(sb + (size_t)row*1024 + half*32 + i*4);
        *(float4*)(&t[row*68 + half*32 + i*4]) = v;
      }
    }
    __syncthreads();
    char* dstb = Vt + ((size_t)bh*NTILE + 16 + tz)*16384;
    #pragma unroll
    for (int u=0;u<4;u++){
      int c = tid + u*256;
      int d = c >> 4;
      int vc = (c & 15) ^ (d & 7);
      int g = vc >> 1, hi = vc & 1;
      int kb_ = 32*(g>>1) + 16*(g&1) + 4*hi;
      uint4 o;
      o.x = pack2f16(t[(kb_+0)*68+d],  t[(kb_+1)*68+d]);
      o.y = pack2f16(t[(kb_+2)*68+d],  t[(kb_+3)*68+d]);
      o.z = pack2f16(t[(kb_+8)*68+d],  t[(kb_+9)*68+d]);
      o.w = pack2f16(t[(kb_+10)*68+d], t[(kb_+11)*68+d]);
      *(uint4*)(dstb + c*16) = o;
    }
  }
}

// -------------------------------------------------------------- flash attention
// NON-SPLIT, 128-key staging tiles (26 iterations, 1 barrier each; 64KB LDS).
// Fixed-max softmax (p = 2^s exact-bounded), pkrtz + fdot2 dual-lsum,
// fully-masked latent 128-tiles skipped, gate fused into the f16 epilogue.
__launch_bounds__(256, 2)
__global__ void attn_fwd(const f16* __restrict__ Qall, const char* __restrict__ Kt,
                         const char* __restrict__ Vt, const int* __restrict__ spp,
                         const f16* __restrict__ gateS, f16* __restrict__ go){
  __shared__ __align__(16) char Ks[2][16384];
  __shared__ __align__(16) char Vs[2][16384];
  const int sp = *spp;
  const int tid = threadIdx.x, lane = tid & 63, w = tid >> 6;
  const int l31 = lane & 31, hi = lane >> 5, l7 = lane & 7;
  const int bid = blockIdx.x;
  const int bh = (bid&7)*4 + ((bid>>3)>>4);   // 64 blocks per XCD share 4 bh
  const int qb = (bid>>3) & 15;
  const int b = bh >> 4, h = bh & 15;
  const int q0w = qb*128 + w*32;
  const f16*  Qb = Qall + (size_t)bh*SS*DD;
  const char* Kb = Kt + (size_t)bh*NTILE*16384;
  const char* Vb = Vt + (size_t)bh*NTILE*16384;

  // 128-key tiles 0..25; latent = 16,17. Skip fully-masked ones.
  const int vl   = min(256, (sp + 3) >> 2);   // valid latent keys
  const int Ms   = 16 + ((vl + 127) >> 7);    // first fully-masked tile (16..18)
  const int skip = 18 - Ms;                   // 0..2 tiles skipped
  const int nt   = 26 - skip;
  #define TMAP(ti) ((ti) < Ms ? (ti) : (ti) + skip)

  f16x8 qf[4];
  {
    const f16* qrow = Qb + (size_t)(q0w + l31)*DD + hi*8;
    #pragma unroll
    for (int ks=0; ks<4; ks++) qf[ks] = *(const f16x8*)(qrow + ks*16);
  }

  f32x16 oA = {0,0,0,0,0,0,0,0,0,0,0,0,0,0,0,0};
  f32x16 oB = {0,0,0,0,0,0,0,0,0,0,0,0,0,0,0,0};
  float lsum0 = 0.f, lsum1 = 0.f;
  const h16x2 ones2 = {(__fp16)1.f, (__fp16)1.f};

  // stage full 16KB K' + V' tiles, linear copy
  #define STAGE(bi, T) do { \
    const char* kb_ = Kb + (size_t)(T)*16384; \
    const char* vb_ = Vb + (size_t)(T)*16384; \
    _Pragma("unroll") \
    for (int u=0; u<4; ++u){ \
      int c = tid + u*256; \
      __builtin_amdgcn_global_load_lds((gptr_t)(kb_ + c*16), (lptr_t)(&Ks[bi][c*16]), 16, 0, 0); \
      __builtin_amdgcn_global_load_lds((gptr_t)(vb_ + c*16), (lptr_t)(&Vs[bi][c*16]), 16, 0, 0); \
    } \
  } while(0)

  STAGE(0, TMAP(0));
  for (int ti = 0; ti < nt; ++ti){
    __syncthreads();
    if (ti < nt-1) STAGE((ti+1)&1, TMAP(ti+1));
    const char* Ksb = Ks[ti&1];
    const char* Vsb = Vs[ti&1];
    const int T = TMAP(ti);
    const bool maskt = (unsigned)(T-16) < 2u;   // latent 128-key tiles 16,17
    const int ktl = (T-16)*128;
    #pragma unroll
    for (int kb=0; kb<4; ++kb){
      f16x8 kf[4];
      #pragma unroll
      for (int ks=0; ks<4; ks++)
        kf[ks] = *(const f16x8*)(Ksb + (32*kb + l31)*128 + (((2*ks+hi) ^ l7))*16);
      f32x16 acc = {0,0,0,0,0,0,0,0,0,0,0,0,0,0,0,0};
      __builtin_amdgcn_s_setprio(1);
      #pragma unroll
      for (int ks=0; ks<4; ks++)
        acc = __builtin_amdgcn_mfma_f32_32x32x16_f16(kf[ks], qf[ks], acc, 0,0,0);
      __builtin_amdgcn_s_setprio(0);
      if (maskt){
        #pragma unroll
        for (int r=0;r<16;r++){
          int kk = ktl + kb*32 + (r&3) + 8*(r>>2) + 4*hi;
          if (kk*4 >= sp) acc[r] = -1e5f;
        }
      }
      // fixed-max softmax: p = 2^s (bounded by 2^11.54 < f16 max).
      // pkrtz packs the pair in 1 instr; fdot2 with ones accumulates lsum
      // from the SAME rounded f16 values that feed PV. Two lsum chains (ILP).
      uint32_t pk[8];
      #pragma unroll
      for (int i=0;i<8;i++){
        float p0 = __builtin_amdgcn_exp2f(acc[2*i]);
        float p1 = __builtin_amdgcn_exp2f(acc[2*i+1]);
        h16x2 h2 = __builtin_amdgcn_cvt_pkrtz(p0, p1);
#if __has_builtin(__builtin_amdgcn_fdot2)
        if (i & 1) lsum1 = __builtin_amdgcn_fdot2(h2, ones2, lsum1, false);
        else       lsum0 = __builtin_amdgcn_fdot2(h2, ones2, lsum0, false);
#else
        if (i & 1) lsum1 += (float)h2[0] + (float)h2[1];
        else       lsum0 += (float)h2[0] + (float)h2[1];
#endif
        union { h16x2 v; uint32_t u; } cv; cv.v = h2; pk[i] = cv.u;
      }
      __builtin_amdgcn_s_setprio(1);
      #pragma unroll
      for (int gg=0; gg<2; gg++){
        union { uint4 u; f16x8 v; } pa;
        pa.u = make_uint4(pk[4*gg], pk[4*gg+1], pk[4*gg+2], pk[4*gg+3]);
        int cofs = ((2*(2*kb+gg) + hi) ^ l7)*16;
        f16x8 v0 = *(const f16x8*)(Vsb + l31*256 + cofs);
        f16x8 v1 = *(const f16x8*)(Vsb + (32+l31)*256 + cofs);
        oA = __builtin_amdgcn_mfma_f32_32x32x16_f16(pa.v, v0, oA, 0,0,0);
        oB = __builtin_amdgcn_mfma_f32_32x32x16_f16(pa.v, v1, oB, 0,0,0);
      }
      __builtin_amdgcn_s_setprio(0);
    }
  }
  #undef STAGE
  #undef TMAP

  float lsum = lsum0 + lsum1;
  lsum += __shfl_xor(lsum, 32, 64);
  float linv = 1.f / lsum;
  #pragma unroll
  for (int r=0;r<16;r++){
    int qo = (r&3) + 8*(r>>2) + 4*hi;
    float nv = __shfl(linv, qo, 64);
    size_t token = (size_t)(b*SS + q0w + qo);
    const f16* gr = gateS + token*1024 + h*64;
    float s0_ = (float)gr[l31], s1_ = (float)gr[32 + l31];
    f16* orow = go + token*1024 + h*64;
    orow[l31]      = (f16)(oA[r]*nv*s0_);
    orow[32 + l31] = (f16)(oB[r]*nv*s1_);
  }
}

// ---------------------------------------------------------------------- launch
extern "C" void kernel_launch(void* const* d_in, const int* in_sizes, int n_in,
                              void* d_out, int out_size, void* d_ws, size_t ws_size,
                              hipStream_t stream){
  const float* x        = (const float*)d_in[0];
  const float* fcos     = (const float*)d_in[3];
  const float* fsin     = (const float*)d_in[4];
  const float* kv_txt_k = (const float*)d_in[5];
  const float* kv_txt_v = (const float*)d_in[6];
  const float* kv_spk_k = (const float*)d_in[7];
  const float* kv_spk_v = (const float*)d_in[8];
  const float* kv_lat_k = (const float*)d_in[9];
  const float* kv_lat_v = (const float*)d_in[10];
  const int*   sp       = (const int*)d_in[11];
  const float* wq       = (const float*)d_in[12];
  const float* wk       = (const float*)d_in[13];
  const float* wv       = (const float*)d_in[14];
  const float* gw       = (const float*)d_in[15];
  const float* wo       = (const float*)d_in[16];
  const float* qnw      = (const float*)d_in[17];
  const float* knw      = (const float*)d_in[18];
  float* out = (float*)d_out;
  char* ws = (char*)d_ws;

  f16*   xh     = (f16*)  (ws + 0);          // 8 MB
  f16*   WtQKVG = (f16*)  (ws + 8388608);    // 8 MB
  f16*   WtO    = (f16*)  (ws + 16777216);   // 2 MB
  f16*   gateS  = (f16*)  (ws + 18874368);   // 8 MB  f16 sigma(gate)
  f16*   Qall   = (f16*)  (ws + 27262976);   // 8 MB  (B,H,S,D)
  char*  Kt     = (char*) (ws + 35651584);   // 13.6 MB K' tiles
  char*  Vt     = (char*) (ws + 49283072);   // 13.6 MB V' tiles
  f16*   go     = (f16*)  (ws + 62914560);   // 8 MB

  prep_all<<<9216, 256, 0, stream>>>(x, xh, wq, wk, wv, gw, wo, WtQKVG, WtO);

  gemm_qkvg<<<1024, 256, 0, stream>>>(xh, WtQKVG, qnw, knw, fcos, fsin, sp,
                                      Qall, Kt, Vt, gateS);

  pack_all<<<2880, 256, 0, stream>>>(kv_lat_k, kv_txt_k, kv_spk_k,
                                     kv_lat_v, kv_txt_v, kv_spk_v, Kt, Vt);

  attn_fwd<<<512, 256, 0, stream>>>(Qall, Kt, Vt, sp, gateS, go);

  gemm_out<<<512, 256, 0, stream>>>(go, WtO, out);
}